// Round 4
// baseline (316.293 us; speedup 1.0000x reference)
//
#include <hip/hip_runtime.h>

#define V      6890
#define NJ     24
#define NB     10
#define NP     207
#define NK     19
#define NBATCH 2048
#define KP     224      // padded K: 10 beta + 207 lrotmin + 1 const + 6 zero
#define KC     217      // constant-1 column (-> v_template)
#define VC     (V*3)    // 20670
#define VCP    20736    // padded VC (= 108*64*3)
#define BN     32       // n-tile
#define BV     64       // v-tile per block
#define NSPLIT 16
#define ITERS  (NBATCH/BN/NSPLIT)   // 4 n-tiles per block
#define VST4   260      // vhsm row stride in shorts (520 B: 8B-aligned, jg-groups 8 banks apart)
#define VSEG   1723     // ceil(V/4) for V-splits

using bh8   = __attribute__((ext_vector_type(8))) short;          // 8 x bf16
using u16x4 = __attribute__((ext_vector_type(4))) unsigned short;
using f32x4 = __attribute__((ext_vector_type(4))) float;

__constant__ int PAR[NJ] = {-1,0,0,0,1,2,3,4,5,6,7,8,9,9,9,12,13,14,16,17,18,19,20,21};

__device__ __forceinline__ unsigned short f2bf(float f) {
    unsigned int u = __float_as_uint(f);
    u += 0x7FFFu + ((u >> 16) & 1u);   // RNE; no NaNs in this data
    return (unsigned short)(u >> 16);
}
__device__ __forceinline__ float bf2f(unsigned short h) {
    return __uint_as_float((unsigned int)h << 16);
}

// ---------------- K_prep: fused [k_jb(V-split, atomic) | k_bmat(K-tiled) | k_jt] ----------------
__global__ __launch_bounds__(256) void k_prep(const float* __restrict__ Jreg,
                                              const float* __restrict__ vtmpl,
                                              const float* __restrict__ sdirs,
                                              const float* __restrict__ pdirs,
                                              const float* __restrict__ jreg,
                                              float* __restrict__ JB,
                                              unsigned short* __restrict__ Bmat,
                                              float* __restrict__ jregT) {
    int blk = blockIdx.x, tid = threadIdx.x;
    if (blk < 792) {                       // JB partial dots, 4-way V-split, atomic accumulate
        int vs = blk & 3, og = blk >> 2;
        int o = og*4 + (tid >> 6);         // o in [0,792) = 24*33
        int lane = tid & 63;
        int j = o/33, t = o%33, c = t/11, m = t%11;
        int lo = vs*VSEG + lane, hi = min(V, vs*VSEG + VSEG);
        const float* jr = Jreg + j*V;
        float s = 0.f;
        if (m == 0) { for (int v = lo; v < hi; v += 64) s += jr[v] * vtmpl[v*3 + c]; }
        else        { for (int v = lo; v < hi; v += 64) s += jr[v] * sdirs[(v*3 + c)*NB + (m-1)]; }
        #pragma unroll
        for (int d = 1; d < 64; d <<= 1) s += __shfl_xor(s, d);
        if (lane == 0) atomicAdd(&JB[(j*3 + c)*11 + m], s);
    } else if (blk < 792 + 18144) {        // Bmat, K-tiled layout [k/32][vc][32]
        int gid = (blk - 792)*256 + tid;   // covers VCP*KP
        int vc = gid / KP, k = gid - vc*KP;
        float val;
        if (vc >= VC)     val = 0.f;
        else if (k < NB)  val = sdirs[vc*NB + k];
        else if (k < KC)  val = pdirs[vc*NP + (k - NB)];
        else if (k == KC) val = vtmpl[vc];
        else              val = 0.f;
        Bmat[((size_t)(k >> 5)*VCP + vc)*32 + (k & 31)] = f2bf(val);
    } else {                               // jregT[k][v]
        int idx = (blk - 792 - 18144)*256 + tid;
        if (idx < NK*V) { int k = idx / V, v = idx - k*V; jregT[idx] = jreg[v*NK + k]; }
    }
}

// ---------------- K_pern: one WAVE per n (64-thread block; barriers ~free) ----------------
__global__ __launch_bounds__(64) void k_pern(const float* __restrict__ beta,
                                             const float* __restrict__ theta,
                                             const float* __restrict__ trans,
                                             const float* __restrict__ JB,
                                             unsigned short* __restrict__ Arow,
                                             unsigned short* __restrict__ Gt) {
    int n = blockIdx.x, tid = threadIdx.x;
    __shared__ float Rsm[NJ][9];
    __shared__ float Jsm[NJ][3];
    __shared__ float Gsm[NJ][12];   // 3x4, e = a*4+b

    if (tid < NJ) {                 // lanes 0-23: rodrigues
        const float* th = theta + (n*NJ + tid)*3;
        float x = th[0], y = th[1], z = th[2];
        float nrm = sqrtf(x*x + y*y + z*z);
        float t = fmaxf(nrm, 1.1754944e-38f);
        float inv = 1.0f / t;
        float rx = x*inv, ry = y*inv, rz = z*inv;
        float c = cosf(t), s = sinf(t), oc = 1.0f - c;
        Rsm[tid][0] = c + oc*rx*rx;      Rsm[tid][1] = oc*rx*ry - s*rz;  Rsm[tid][2] = oc*rx*rz + s*ry;
        Rsm[tid][3] = oc*ry*rx + s*rz;   Rsm[tid][4] = c + oc*ry*ry;     Rsm[tid][5] = oc*ry*rz - s*rx;
        Rsm[tid][6] = oc*rz*rx - s*ry;   Rsm[tid][7] = oc*rz*ry + s*rx;  Rsm[tid][8] = c + oc*rz*rz;
    } else if (tid < 2*NJ) {        // lanes 24-47: J rows (3 dots of 11 each)
        int j = tid - NJ;
        #pragma unroll
        for (int c = 0; c < 3; ++c) {
            float s = JB[(j*3+c)*11 + 0];
            #pragma unroll
            for (int b = 0; b < NB; ++b) s += JB[(j*3+c)*11 + 1 + b] * beta[n*NB + b];
            Jsm[j][c] = s;
        }
    }
    __syncthreads();

    if (tid < 12) {
        int a = tid >> 2, b = tid & 3;
        Gsm[0][a*4+b] = (b < 3) ? Rsm[0][a*3+b] : Jsm[0][a];
    }
    __syncthreads();
    for (int i = 1; i < NJ; ++i) {
        if (tid < 12) {
            int a = tid >> 2, b = tid & 3;
            int p = PAR[i];
            float acc = (b == 3) ? Gsm[p][a*4+3] : 0.0f;
            #pragma unroll
            for (int k = 0; k < 3; ++k) {
                float aval = (b < 3) ? Rsm[i][k*3+b] : (Jsm[i][k] - Jsm[p][k]);
                acc += Gsm[p][a*4+k] * aval;
            }
            Gsm[i][a*4+b] = acc;
        }
        __syncthreads();
    }
    if (tid < NJ) {   // t' = t - R.J + trans (trans folds: sum_j w = 1)
        int j = tid;
        #pragma unroll
        for (int a = 0; a < 3; ++a) {
            float t3 = Gsm[j][a*4+3]
                     - (Gsm[j][a*4+0]*Jsm[j][0] + Gsm[j][a*4+1]*Jsm[j][1] + Gsm[j][a*4+2]*Jsm[j][2])
                     + trans[n*3 + a];
            Gsm[j][a*4+3] = t3;
        }
    }
    __syncthreads();
    // Gt[n][e=0..15][j=0..31] bf16 zero-padded
    unsigned short* gt = Gt + n*512;
    for (int idx = tid; idx < 512; idx += 64) {
        int e = idx >> 5, j = idx & 31;
        float val = (e < 12 && j < NJ) ? Gsm[j][e] : 0.0f;
        gt[idx] = f2bf(val);
    }
    // A-row, K-tiled layout [k/32][n][32]
    for (int k = tid; k < KP; k += 64) {
        float val;
        if (k < NB) val = beta[n*NB + k];
        else if (k < KC) {
            int p = k - NB; int jj = p/9 + 1; int rr = p%9;
            val = Rsm[jj][rr] - ((rr==0 || rr==4 || rr==8) ? 1.0f : 0.0f);
        } else if (k == KC) val = 1.0f;
        else val = 0.0f;
        Arow[((size_t)(k >> 5)*NBATCH + n)*32 + (k & 31)] = f2bf(val);
    }
}

// ---------------- K_main: persistent n-loop; hoisted+pinned B/W frags; MFMA GEMM1+GEMM2 ----------------
__global__ __launch_bounds__(256) void k_main(const unsigned short* __restrict__ Arow,
                                              const unsigned short* __restrict__ Bmat,
                                              const unsigned short* __restrict__ Gt,
                                              const float* __restrict__ weights,
                                              float* __restrict__ verts) {
    __shared__ __attribute__((aligned(16))) unsigned short vhsm[BN*VST4];   // 16640 B

    int tid = threadIdx.x;
    int wv = tid >> 6, lane = tid & 63;
    int l15 = lane & 15, jg = lane >> 4;
    int ns = blockIdx.x, vb = blockIdx.y;
    int v0 = vb * BV, vc0 = v0 * 3;
    int vcw0 = vc0 + wv*48;             // this wave's 48 vc columns

    // ---- hoist B fragments (7 ks x 3 ct), pinned against rematerialization ----
    bh8 bfr[7][3];
    #pragma unroll
    for (int ks = 0; ks < 7; ++ks)
        #pragma unroll
        for (int ct = 0; ct < 3; ++ct)
            bfr[ks][ct] = *(const bh8*)(Bmat + ((size_t)ks*VCP + vcw0 + ct*16 + l15)*32 + jg*8);
    #pragma unroll
    for (int ks = 0; ks < 7; ++ks)
        #pragma unroll
        for (int ct = 0; ct < 3; ++ct)
            asm volatile("" : "+v"(bfr[ks][ct]));

    // ---- W fragments (B-operand of GEMM2), pinned ----
    bh8 wfrag[4];
    #pragma unroll
    for (int mt = 0; mt < 4; ++mt) {
        int vr = v0 + mt*16 + l15;
        bh8 f = {0,0,0,0,0,0,0,0};
        if (jg < 3 && vr < V) {
            const float4* wp = (const float4*)(weights + (size_t)vr*NJ + jg*8);
            float4 w0 = wp[0], w1 = wp[1];
            f[0]=(short)f2bf(w0.x); f[1]=(short)f2bf(w0.y); f[2]=(short)f2bf(w0.z); f[3]=(short)f2bf(w0.w);
            f[4]=(short)f2bf(w1.x); f[5]=(short)f2bf(w1.y); f[6]=(short)f2bf(w1.z); f[7]=(short)f2bf(w1.w);
        }
        wfrag[mt] = f;
    }
    #pragma unroll
    for (int mt = 0; mt < 4; ++mt) asm volatile("" : "+v"(wfrag[mt]));

    // per-lane spill column mapping (vc -> padded-4 col), constant across iters
    int c4[3];
    #pragma unroll
    for (int ct = 0; ct < 3; ++ct) {
        int vcw = wv*48 + ct*16 + l15;          // [0,192)
        c4[ct] = (vcw/3)*4 + vcw%3;
    }
    int tri = (((lane % 3)*16) + lane/3) * 4;   // bpermute byte index for output transpose

    #pragma unroll 1
    for (int it = 0; it < ITERS; ++it) {
        int n0 = (ns*ITERS + it) * BN;

        // ---- A fragments for this n-tile (batched issue, one wait) ----
        bh8 af[7][2];
        #pragma unroll
        for (int ks = 0; ks < 7; ++ks)
            #pragma unroll
            for (int mt = 0; mt < 2; ++mt)
                af[ks][mt] = *(const bh8*)(Arow + ((size_t)ks*NBATCH + n0 + mt*16 + l15)*32 + jg*8);
        #pragma unroll
        for (int ks = 0; ks < 7; ++ks)
            #pragma unroll
            for (int mt = 0; mt < 2; ++mt)
                asm volatile("" : "+v"(af[ks][mt]));

        // ---- GEMM1: vh = Arow . Bmat^T (all operands in registers) ----
        f32x4 acc[2][3] = {};
        #pragma unroll
        for (int ks = 0; ks < 7; ++ks)
            #pragma unroll
            for (int mt = 0; mt < 2; ++mt)
                #pragma unroll
                for (int ct = 0; ct < 3; ++ct)
                    acc[mt][ct] = __builtin_amdgcn_mfma_f32_16x16x32_bf16(af[ks][mt], bfr[ks][ct], acc[mt][ct], 0, 0, 0);

        __syncthreads();    // prev iter's GEMM2 reads done
        // spill (bf16, padded-4): row = n_local, col = v*4+b
        #pragma unroll
        for (int mt = 0; mt < 2; ++mt)
            #pragma unroll
            for (int ct = 0; ct < 3; ++ct)
                #pragma unroll
                for (int r = 0; r < 4; ++r)
                    vhsm[(mt*16 + jg*4 + r)*VST4 + c4[ct]] = f2bf(acc[mt][ct][r]);
        __syncthreads();

        // ---- GEMM2 + apply + transpose + NT store ----
        const unsigned short* gbase = Gt + ((size_t)(n0 + wv*8))*512 + l15*32 + jg*8;
        bh8 gcur = *(const bh8*)gbase;
        #pragma unroll
        for (int nl = 0; nl < 8; ++nl) {
            bh8 gnxt = gcur;
            if (nl < 7) gnxt = *(const bh8*)(gbase + (nl+1)*512);
            int n_loc = wv*8 + nl;
            #pragma unroll
            for (int mt = 0; mt < 4; ++mt) {
                f32x4 z = {0.f, 0.f, 0.f, 0.f};
                f32x4 t = __builtin_amdgcn_mfma_f32_16x16x32_bf16(gcur, wfrag[mt], z, 0, 0, 0);
                u16x4 vh4 = *(const u16x4*)&vhsm[n_loc*VST4 + (mt*16 + l15)*4];
                float p = t[0]*bf2f(vh4[0]) + t[1]*bf2f(vh4[1]) + t[2]*bf2f(vh4[2]) + t[3];
                float pp = __int_as_float(__builtin_amdgcn_ds_bpermute(tri, __float_as_int(p)));
                int col = vc0 + mt*48 + lane;
                if (lane < 48 && col < VC)
                    __builtin_nontemporal_store(pp, verts + (size_t)(n0 + n_loc)*VC + col);
            }
            gcur = gnxt;
        }
    }
}

// ---------------- K_joints: 4-way V-split, atomic accumulate (joints pre-zeroed) ----------------
__global__ __launch_bounds__(256) void k_joints(const float* __restrict__ verts,
                                                const float* __restrict__ jregT,
                                                float* __restrict__ joints) {
    int n = blockIdx.x, vs = blockIdx.y, tid = threadIdx.x;
    int lo = vs*VSEG, hi = min(V, lo + VSEG);
    float acc[NK*3];
    #pragma unroll
    for (int i = 0; i < NK*3; ++i) acc[i] = 0.f;
    const float* vr = verts + (size_t)n*VC;
    for (int v = lo + tid; v < hi; v += 256) {
        float x = __builtin_nontemporal_load(vr + v*3 + 0);
        float y = __builtin_nontemporal_load(vr + v*3 + 1);
        float z = __builtin_nontemporal_load(vr + v*3 + 2);
        #pragma unroll
        for (int k = 0; k < NK; ++k) {
            float w = jregT[k*V + v];
            acc[k*3+0] += w*x; acc[k*3+1] += w*y; acc[k*3+2] += w*z;
        }
    }
    __shared__ float red[4][NK*3];
    #pragma unroll
    for (int i = 0; i < NK*3; ++i) {
        float s = acc[i];
        #pragma unroll
        for (int d = 1; d < 64; d <<= 1) s += __shfl_xor(s, d);
        if ((tid & 63) == 0) red[tid >> 6][i] = s;
    }
    __syncthreads();
    if (tid < NK*3)
        atomicAdd(&joints[n*NK*3 + tid], red[0][tid] + red[1][tid] + red[2][tid] + red[3][tid]);
}

extern "C" void kernel_launch(void* const* d_in, const int* in_sizes, int n_in,
                              void* d_out, int out_size, void* d_ws, size_t ws_size,
                              hipStream_t stream) {
    const float* beta  = (const float*)d_in[0];
    const float* theta = (const float*)d_in[1];
    const float* trans = (const float*)d_in[2];
    const float* sdirs = (const float*)d_in[3];
    const float* vtmpl = (const float*)d_in[4];
    const float* jregJ = (const float*)d_in[5];
    const float* pdirs = (const float*)d_in[6];
    const float* wgts  = (const float*)d_in[7];
    const float* jregK = (const float*)d_in[8];

    float* verts  = (float*)d_out;
    float* joints = verts + (size_t)NBATCH * VC;

    char* ws = (char*)d_ws;
    float*          JB    = (float*)ws;                                      // 4096 B (zeroed)
    unsigned short* Arow  = (unsigned short*)(ws + 4096);                    // 917504 B
    unsigned short* Gt    = (unsigned short*)(ws + 4096 + 917504);           // 2097152 B
    unsigned short* Bmat  = (unsigned short*)(ws + 4096 + 917504 + 2097152); // 9289728 B
    float*          jregT = (float*)(ws + 4096 + 917504 + 2097152 + 9289728);// 523640 B

    hipMemsetAsync(JB, 0, 4096, stream);
    hipMemsetAsync(joints, 0, (size_t)NBATCH*NK*3*sizeof(float), stream);

    k_prep <<<792 + 18144 + 512, 256, 0, stream>>>(jregJ, vtmpl, sdirs, pdirs, jregK, JB, Bmat, jregT);
    k_pern <<<NBATCH, 64, 0, stream>>>(beta, theta, trans, JB, Arow, Gt);
    dim3 g4(NSPLIT, (V + BV - 1)/BV);   // (16, 108)
    k_main <<<g4, 256, 0, stream>>>(Arow, Bmat, Gt, wgts, verts);
    dim3 g5(NBATCH, 4);
    k_joints<<<g5, 256, 0, stream>>>(verts, jregT, joints);
}

// Round 5
// 240.822 us; speedup vs baseline: 1.3134x; 1.3134x over previous
//
#include <hip/hip_runtime.h>

#define V      6890
#define NJ     24
#define NB     10
#define NP     207
#define NK     19
#define NBATCH 2048
#define KP     224      // padded K: 10 beta + 207 lrotmin + 1 const + 6 zero
#define KC     217      // constant-1 column (-> v_template)
#define VC     (V*3)    // 20670
#define VCP    20736    // padded VC (= 108*64*3)
#define BN     32       // n-tile
#define BV     64       // v-tile per block
#define NSPLIT 16
#define ITERS  (NBATCH/BN/NSPLIT)   // 4 n-tiles per block
#define VST4   260      // vhsm row stride in shorts (520 B: 8B-aligned, jg-groups 8 banks apart)
#define VSEG   1723     // ceil(V/4) for V-splits (k_prep JB dots)

using bh8   = __attribute__((ext_vector_type(8))) short;          // 8 x bf16
using u16x4 = __attribute__((ext_vector_type(4))) unsigned short;
using f32x4 = __attribute__((ext_vector_type(4))) float;

__constant__ int PAR[NJ] = {-1,0,0,0,1,2,3,4,5,6,7,8,9,9,9,12,13,14,16,17,18,19,20,21};

__device__ __forceinline__ unsigned short f2bf(float f) {
    unsigned int u = __float_as_uint(f);
    u += 0x7FFFu + ((u >> 16) & 1u);   // RNE; no NaNs in this data
    return (unsigned short)(u >> 16);
}
__device__ __forceinline__ float bf2f(unsigned short h) {
    return __uint_as_float((unsigned int)h << 16);
}

// ---------------- K_prep: fused [k_jb(V-split, atomic) | k_bmat(K-tiled) | k_jt] ----------------
__global__ __launch_bounds__(256) void k_prep(const float* __restrict__ Jreg,
                                              const float* __restrict__ vtmpl,
                                              const float* __restrict__ sdirs,
                                              const float* __restrict__ pdirs,
                                              const float* __restrict__ jreg,
                                              float* __restrict__ JB,
                                              unsigned short* __restrict__ Bmat,
                                              float* __restrict__ jregT) {
    int blk = blockIdx.x, tid = threadIdx.x;
    if (blk < 792) {                       // JB partial dots, 4-way V-split, atomic accumulate
        int vs = blk & 3, og = blk >> 2;
        int o = og*4 + (tid >> 6);         // o in [0,792) = 24*33
        int lane = tid & 63;
        int j = o/33, t = o%33, c = t/11, m = t%11;
        int lo = vs*VSEG + lane, hi = min(V, vs*VSEG + VSEG);
        const float* jr = Jreg + j*V;
        float s = 0.f;
        if (m == 0) { for (int v = lo; v < hi; v += 64) s += jr[v] * vtmpl[v*3 + c]; }
        else        { for (int v = lo; v < hi; v += 64) s += jr[v] * sdirs[(v*3 + c)*NB + (m-1)]; }
        #pragma unroll
        for (int d = 1; d < 64; d <<= 1) s += __shfl_xor(s, d);
        if (lane == 0) atomicAdd(&JB[(j*3 + c)*11 + m], s);
    } else if (blk < 792 + 18144) {        // Bmat, K-tiled layout [k/32][vc][32]
        int gid = (blk - 792)*256 + tid;   // covers VCP*KP
        int vc = gid / KP, k = gid - vc*KP;
        float val;
        if (vc >= VC)     val = 0.f;
        else if (k < NB)  val = sdirs[vc*NB + k];
        else if (k < KC)  val = pdirs[vc*NP + (k - NB)];
        else if (k == KC) val = vtmpl[vc];
        else              val = 0.f;
        Bmat[((size_t)(k >> 5)*VCP + vc)*32 + (k & 31)] = f2bf(val);
    } else {                               // jregT[k][v]
        int idx = (blk - 792 - 18144)*256 + tid;
        if (idx < NK*V) { int k = idx / V, v = idx - k*V; jregT[idx] = jreg[v*NK + k]; }
    }
}

// ---------------- K_pern: one WAVE per n (64-thread block; barriers ~free) ----------------
__global__ __launch_bounds__(64) void k_pern(const float* __restrict__ beta,
                                             const float* __restrict__ theta,
                                             const float* __restrict__ trans,
                                             const float* __restrict__ JB,
                                             unsigned short* __restrict__ Arow,
                                             unsigned short* __restrict__ Gt) {
    int n = blockIdx.x, tid = threadIdx.x;
    __shared__ float Rsm[NJ][9];
    __shared__ float Jsm[NJ][3];
    __shared__ float Gsm[NJ][12];   // 3x4, e = a*4+b

    if (tid < NJ) {                 // lanes 0-23: rodrigues
        const float* th = theta + (n*NJ + tid)*3;
        float x = th[0], y = th[1], z = th[2];
        float nrm = sqrtf(x*x + y*y + z*z);
        float t = fmaxf(nrm, 1.1754944e-38f);
        float inv = 1.0f / t;
        float rx = x*inv, ry = y*inv, rz = z*inv;
        float c = cosf(t), s = sinf(t), oc = 1.0f - c;
        Rsm[tid][0] = c + oc*rx*rx;      Rsm[tid][1] = oc*rx*ry - s*rz;  Rsm[tid][2] = oc*rx*rz + s*ry;
        Rsm[tid][3] = oc*ry*rx + s*rz;   Rsm[tid][4] = c + oc*ry*ry;     Rsm[tid][5] = oc*ry*rz - s*rx;
        Rsm[tid][6] = oc*rz*rx - s*ry;   Rsm[tid][7] = oc*rz*ry + s*rx;  Rsm[tid][8] = c + oc*rz*rz;
    } else if (tid < 2*NJ) {        // lanes 24-47: J rows (3 dots of 11 each)
        int j = tid - NJ;
        #pragma unroll
        for (int c = 0; c < 3; ++c) {
            float s = JB[(j*3+c)*11 + 0];
            #pragma unroll
            for (int b = 0; b < NB; ++b) s += JB[(j*3+c)*11 + 1 + b] * beta[n*NB + b];
            Jsm[j][c] = s;
        }
    }
    __syncthreads();

    if (tid < 12) {
        int a = tid >> 2, b = tid & 3;
        Gsm[0][a*4+b] = (b < 3) ? Rsm[0][a*3+b] : Jsm[0][a];
    }
    __syncthreads();
    for (int i = 1; i < NJ; ++i) {
        if (tid < 12) {
            int a = tid >> 2, b = tid & 3;
            int p = PAR[i];
            float acc = (b == 3) ? Gsm[p][a*4+3] : 0.0f;
            #pragma unroll
            for (int k = 0; k < 3; ++k) {
                float aval = (b < 3) ? Rsm[i][k*3+b] : (Jsm[i][k] - Jsm[p][k]);
                acc += Gsm[p][a*4+k] * aval;
            }
            Gsm[i][a*4+b] = acc;
        }
        __syncthreads();
    }
    if (tid < NJ) {   // t' = t - R.J + trans (trans folds: sum_j w = 1)
        int j = tid;
        #pragma unroll
        for (int a = 0; a < 3; ++a) {
            float t3 = Gsm[j][a*4+3]
                     - (Gsm[j][a*4+0]*Jsm[j][0] + Gsm[j][a*4+1]*Jsm[j][1] + Gsm[j][a*4+2]*Jsm[j][2])
                     + trans[n*3 + a];
            Gsm[j][a*4+3] = t3;
        }
    }
    __syncthreads();
    // Gt[n][e=0..15][j=0..31] bf16 zero-padded
    unsigned short* gt = Gt + n*512;
    for (int idx = tid; idx < 512; idx += 64) {
        int e = idx >> 5, j = idx & 31;
        float val = (e < 12 && j < NJ) ? Gsm[j][e] : 0.0f;
        gt[idx] = f2bf(val);
    }
    // A-row, K-tiled layout [k/32][n][32]
    for (int k = tid; k < KP; k += 64) {
        float val;
        if (k < NB) val = beta[n*NB + k];
        else if (k < KC) {
            int p = k - NB; int jj = p/9 + 1; int rr = p%9;
            val = Rsm[jj][rr] - ((rr==0 || rr==4 || rr==8) ? 1.0f : 0.0f);
        } else if (k == KC) val = 1.0f;
        else val = 0.0f;
        Arow[((size_t)(k >> 5)*NBATCH + n)*32 + (k & 31)] = f2bf(val);
    }
}

// ---------------- K_main: persistent n-loop; hoisted+pinned B/W frags; MFMA GEMM1+GEMM2 ----------------
__global__ __launch_bounds__(256) void k_main(const unsigned short* __restrict__ Arow,
                                              const unsigned short* __restrict__ Bmat,
                                              const unsigned short* __restrict__ Gt,
                                              const float* __restrict__ weights,
                                              float* __restrict__ verts) {
    __shared__ __attribute__((aligned(16))) unsigned short vhsm[BN*VST4];   // 16640 B

    int tid = threadIdx.x;
    int wv = tid >> 6, lane = tid & 63;
    int l15 = lane & 15, jg = lane >> 4;
    int ns = blockIdx.x, vb = blockIdx.y;
    int v0 = vb * BV, vc0 = v0 * 3;
    int vcw0 = vc0 + wv*48;             // this wave's 48 vc columns

    // ---- hoist B fragments (7 ks x 3 ct), pinned against rematerialization ----
    bh8 bfr[7][3];
    #pragma unroll
    for (int ks = 0; ks < 7; ++ks)
        #pragma unroll
        for (int ct = 0; ct < 3; ++ct)
            bfr[ks][ct] = *(const bh8*)(Bmat + ((size_t)ks*VCP + vcw0 + ct*16 + l15)*32 + jg*8);
    #pragma unroll
    for (int ks = 0; ks < 7; ++ks)
        #pragma unroll
        for (int ct = 0; ct < 3; ++ct)
            asm volatile("" : "+v"(bfr[ks][ct]));

    // ---- W fragments (B-operand of GEMM2), pinned ----
    bh8 wfrag[4];
    #pragma unroll
    for (int mt = 0; mt < 4; ++mt) {
        int vr = v0 + mt*16 + l15;
        bh8 f = {0,0,0,0,0,0,0,0};
        if (jg < 3 && vr < V) {
            const float4* wp = (const float4*)(weights + (size_t)vr*NJ + jg*8);
            float4 w0 = wp[0], w1 = wp[1];
            f[0]=(short)f2bf(w0.x); f[1]=(short)f2bf(w0.y); f[2]=(short)f2bf(w0.z); f[3]=(short)f2bf(w0.w);
            f[4]=(short)f2bf(w1.x); f[5]=(short)f2bf(w1.y); f[6]=(short)f2bf(w1.z); f[7]=(short)f2bf(w1.w);
        }
        wfrag[mt] = f;
    }
    #pragma unroll
    for (int mt = 0; mt < 4; ++mt) asm volatile("" : "+v"(wfrag[mt]));

    // per-lane spill column mapping (vc -> padded-4 col), constant across iters
    int c4[3];
    #pragma unroll
    for (int ct = 0; ct < 3; ++ct) {
        int vcw = wv*48 + ct*16 + l15;          // [0,192)
        c4[ct] = (vcw/3)*4 + vcw%3;
    }
    int tri = (((lane % 3)*16) + lane/3) * 4;   // bpermute byte index for output transpose

    #pragma unroll 1
    for (int it = 0; it < ITERS; ++it) {
        int n0 = (ns*ITERS + it) * BN;

        // ---- A fragments for this n-tile (batched issue, one wait) ----
        bh8 af[7][2];
        #pragma unroll
        for (int ks = 0; ks < 7; ++ks)
            #pragma unroll
            for (int mt = 0; mt < 2; ++mt)
                af[ks][mt] = *(const bh8*)(Arow + ((size_t)ks*NBATCH + n0 + mt*16 + l15)*32 + jg*8);
        #pragma unroll
        for (int ks = 0; ks < 7; ++ks)
            #pragma unroll
            for (int mt = 0; mt < 2; ++mt)
                asm volatile("" : "+v"(af[ks][mt]));

        // ---- GEMM1: vh = Arow . Bmat^T (all operands in registers) ----
        f32x4 acc[2][3] = {};
        #pragma unroll
        for (int ks = 0; ks < 7; ++ks)
            #pragma unroll
            for (int mt = 0; mt < 2; ++mt)
                #pragma unroll
                for (int ct = 0; ct < 3; ++ct)
                    acc[mt][ct] = __builtin_amdgcn_mfma_f32_16x16x32_bf16(af[ks][mt], bfr[ks][ct], acc[mt][ct], 0, 0, 0);

        __syncthreads();    // prev iter's GEMM2 reads done
        // spill (bf16, padded-4): row = n_local, col = v*4+b
        #pragma unroll
        for (int mt = 0; mt < 2; ++mt)
            #pragma unroll
            for (int ct = 0; ct < 3; ++ct)
                #pragma unroll
                for (int r = 0; r < 4; ++r)
                    vhsm[(mt*16 + jg*4 + r)*VST4 + c4[ct]] = f2bf(acc[mt][ct][r]);
        __syncthreads();

        // ---- GEMM2 + apply + transpose + NT store ----
        const unsigned short* gbase = Gt + ((size_t)(n0 + wv*8))*512 + l15*32 + jg*8;
        bh8 gcur = *(const bh8*)gbase;
        #pragma unroll
        for (int nl = 0; nl < 8; ++nl) {
            bh8 gnxt = gcur;
            if (nl < 7) gnxt = *(const bh8*)(gbase + (nl+1)*512);
            int n_loc = wv*8 + nl;
            #pragma unroll
            for (int mt = 0; mt < 4; ++mt) {
                f32x4 z = {0.f, 0.f, 0.f, 0.f};
                f32x4 t = __builtin_amdgcn_mfma_f32_16x16x32_bf16(gcur, wfrag[mt], z, 0, 0, 0);
                u16x4 vh4 = *(const u16x4*)&vhsm[n_loc*VST4 + (mt*16 + l15)*4];
                float p = t[0]*bf2f(vh4[0]) + t[1]*bf2f(vh4[1]) + t[2]*bf2f(vh4[2]) + t[3];
                float pp = __int_as_float(__builtin_amdgcn_ds_bpermute(tri, __float_as_int(p)));
                int col = vc0 + mt*48 + lane;
                if (lane < 48 && col < VC)
                    __builtin_nontemporal_store(pp, verts + (size_t)(n0 + n_loc)*VC + col);
            }
            gcur = gnxt;
        }
    }
}

// ---------------- K_joints: k-split across waves (15 accs/lane, NO spill); LDS vert tiles ----------------
__global__ __launch_bounds__(256) void k_joints(const float* __restrict__ verts,
                                                const float* __restrict__ jregT,
                                                float* __restrict__ joints) {
    int n = blockIdx.x, tid = threadIdx.x;
    int wv = tid >> 6, lane = tid & 63;
    __shared__ float xs[256], ys[256], zs[256];

    int k0 = wv * 5;
    int kn = (wv == 3) ? 4 : 5;          // waves own k = {0-4, 5-9, 10-14, 15-18}
    float acc[5][3];
    #pragma unroll
    for (int kk = 0; kk < 5; ++kk) { acc[kk][0] = 0.f; acc[kk][1] = 0.f; acc[kk][2] = 0.f; }

    const float* vr = verts + (size_t)n * VC;
    for (int t0 = 0; t0 < V; t0 += 256) {
        __syncthreads();
        int v = t0 + tid;
        if (v < V) {
            xs[tid] = vr[v*3 + 0];
            ys[tid] = vr[v*3 + 1];
            zs[tid] = vr[v*3 + 2];
        }
        __syncthreads();
        int lim = min(256, V - t0);
        for (int i = lane; i < lim; i += 64) {
            float x = xs[i], y = ys[i], z = zs[i];
            int vg = t0 + i;
            #pragma unroll
            for (int kk = 0; kk < 5; ++kk) {
                if (kk < kn) {
                    float w = jregT[(k0 + kk)*V + vg];
                    acc[kk][0] += w*x; acc[kk][1] += w*y; acc[kk][2] += w*z;
                }
            }
        }
    }
    #pragma unroll
    for (int kk = 0; kk < 5; ++kk)
        #pragma unroll
        for (int c = 0; c < 3; ++c) {
            float s = acc[kk][c];
            #pragma unroll
            for (int d = 1; d < 64; d <<= 1) s += __shfl_xor(s, d);
            if (lane == 0 && kk < kn)
                joints[(size_t)n*NK*3 + (k0 + kk)*3 + c] = s;
        }
}

extern "C" void kernel_launch(void* const* d_in, const int* in_sizes, int n_in,
                              void* d_out, int out_size, void* d_ws, size_t ws_size,
                              hipStream_t stream) {
    const float* beta  = (const float*)d_in[0];
    const float* theta = (const float*)d_in[1];
    const float* trans = (const float*)d_in[2];
    const float* sdirs = (const float*)d_in[3];
    const float* vtmpl = (const float*)d_in[4];
    const float* jregJ = (const float*)d_in[5];
    const float* pdirs = (const float*)d_in[6];
    const float* wgts  = (const float*)d_in[7];
    const float* jregK = (const float*)d_in[8];

    float* verts  = (float*)d_out;
    float* joints = verts + (size_t)NBATCH * VC;

    char* ws = (char*)d_ws;
    float*          JB    = (float*)ws;                                      // 4096 B (zeroed)
    unsigned short* Arow  = (unsigned short*)(ws + 4096);                    // 917504 B
    unsigned short* Gt    = (unsigned short*)(ws + 4096 + 917504);           // 2097152 B
    unsigned short* Bmat  = (unsigned short*)(ws + 4096 + 917504 + 2097152); // 9289728 B
    float*          jregT = (float*)(ws + 4096 + 917504 + 2097152 + 9289728);// 523640 B

    hipMemsetAsync(JB, 0, 4096, stream);

    k_prep <<<792 + 18144 + 512, 256, 0, stream>>>(jregJ, vtmpl, sdirs, pdirs, jregK, JB, Bmat, jregT);
    k_pern <<<NBATCH, 64, 0, stream>>>(beta, theta, trans, JB, Arow, Gt);
    dim3 g4(NSPLIT, (V + BV - 1)/BV);   // (16, 108)
    k_main <<<g4, 256, 0, stream>>>(Arow, Bmat, Gt, wgts, verts);
    k_joints<<<NBATCH, 256, 0, stream>>>(verts, jregT, joints);
}

// Round 6
// 237.632 us; speedup vs baseline: 1.3310x; 1.0134x over previous
//
#include <hip/hip_runtime.h>

#define V      6890
#define NJ     24
#define NB     10
#define NP     207
#define NK     19
#define NBATCH 2048
#define KP     224      // padded K: 10 beta + 207 lrotmin + 1 const + 6 zero
#define KC     217      // constant-1 column (-> v_template)
#define VC     (V*3)    // 20670
#define VCP    20736    // padded VC (= 108*64*3)
#define BN     32       // n-tile
#define BV     64       // v-tile per block
#define NSPLIT 16
#define ITERS  (NBATCH/BN/NSPLIT)   // 4 n-tiles per block
#define VST4   260      // vhsm row stride in shorts (520 B: 8B-aligned, jg-groups 8 banks apart)
#define VSEG   1723     // ceil(V/4) for V-splits (k_prep JB dots)
#define KSP    16       // joints GEMM K-split
#define KSTEPS 648      // VCP/32
#define KCHUNK 41       // ceil(648/16); last slice gets 33

using bh8   = __attribute__((ext_vector_type(8))) short;          // 8 x bf16
using u16x4 = __attribute__((ext_vector_type(4))) unsigned short;
using f32x4 = __attribute__((ext_vector_type(4))) float;

__constant__ int PAR[NJ] = {-1,0,0,0,1,2,3,4,5,6,7,8,9,9,9,12,13,14,16,17,18,19,20,21};

__device__ __forceinline__ unsigned short f2bf(float f) {
    unsigned int u = __float_as_uint(f);
    u += 0x7FFFu + ((u >> 16) & 1u);   // RNE; no NaNs in this data
    return (unsigned short)(u >> 16);
}
__device__ __forceinline__ float bf2f(unsigned short h) {
    return __uint_as_float((unsigned int)h << 16);
}
__device__ __forceinline__ bh8 ld_cvt8(const float* p) {
    float2 q0 = *(const float2*)(p+0);
    float2 q1 = *(const float2*)(p+2);
    float2 q2 = *(const float2*)(p+4);
    float2 q3 = *(const float2*)(p+6);
    bh8 f;
    f[0]=(short)f2bf(q0.x); f[1]=(short)f2bf(q0.y);
    f[2]=(short)f2bf(q1.x); f[3]=(short)f2bf(q1.y);
    f[4]=(short)f2bf(q2.x); f[5]=(short)f2bf(q2.y);
    f[6]=(short)f2bf(q3.x); f[7]=(short)f2bf(q3.y);
    return f;
}

// ---------------- K_prep: fused [k_jb(V-split, atomic) | k_bmat(K-tiled) | Jbig] ----------------
__global__ __launch_bounds__(256) void k_prep(const float* __restrict__ Jreg,
                                              const float* __restrict__ vtmpl,
                                              const float* __restrict__ sdirs,
                                              const float* __restrict__ pdirs,
                                              const float* __restrict__ jreg,
                                              float* __restrict__ JB,
                                              unsigned short* __restrict__ Bmat,
                                              unsigned short* __restrict__ Jbig) {
    int blk = blockIdx.x, tid = threadIdx.x;
    if (blk < 792) {                       // JB partial dots, 4-way V-split, atomic accumulate
        int vs = blk & 3, og = blk >> 2;
        int o = og*4 + (tid >> 6);         // o in [0,792) = 24*33
        int lane = tid & 63;
        int j = o/33, t = o%33, c = t/11, m = t%11;
        int lo = vs*VSEG + lane, hi = min(V, vs*VSEG + VSEG);
        const float* jr = Jreg + j*V;
        float s = 0.f;
        if (m == 0) { for (int v = lo; v < hi; v += 64) s += jr[v] * vtmpl[v*3 + c]; }
        else        { for (int v = lo; v < hi; v += 64) s += jr[v] * sdirs[(v*3 + c)*NB + (m-1)]; }
        #pragma unroll
        for (int d = 1; d < 64; d <<= 1) s += __shfl_xor(s, d);
        if (lane == 0) atomicAdd(&JB[(j*3 + c)*11 + m], s);
    } else if (blk < 792 + 18144) {        // Bmat, K-tiled layout [k/32][vc][32]
        int gid = (blk - 792)*256 + tid;   // covers VCP*KP
        int vc = gid / KP, k = gid - vc*KP;
        float val;
        if (vc >= VC)     val = 0.f;
        else if (k < NB)  val = sdirs[vc*NB + k];
        else if (k < KC)  val = pdirs[vc*NP + (k - NB)];
        else if (k == KC) val = vtmpl[vc];
        else              val = 0.f;
        Bmat[((size_t)(k >> 5)*VCP + vc)*32 + (k & 31)] = f2bf(val);
    } else {                               // Jbig[kc][vc] bf16: delta(kc%3,vc%3)*jreg[vc/3][kc/3]
        int gid = (blk - 792 - 18144)*256 + tid;   // covers 64*VCP
        int kc = gid / VCP, vc = gid - kc*VCP;
        float val = 0.f;
        if (kc < NK*3 && vc < VC && (kc % 3) == (vc % 3))
            val = jreg[(vc/3)*NK + (kc/3)];
        Jbig[gid] = f2bf(val);
    }
}

// ---------------- K_pern: one WAVE per n (64-thread block; barriers ~free) ----------------
__global__ __launch_bounds__(64) void k_pern(const float* __restrict__ beta,
                                             const float* __restrict__ theta,
                                             const float* __restrict__ trans,
                                             const float* __restrict__ JB,
                                             unsigned short* __restrict__ Arow,
                                             unsigned short* __restrict__ Gt) {
    int n = blockIdx.x, tid = threadIdx.x;
    __shared__ float Rsm[NJ][9];
    __shared__ float Jsm[NJ][3];
    __shared__ float Gsm[NJ][12];   // 3x4, e = a*4+b

    if (tid < NJ) {                 // lanes 0-23: rodrigues
        const float* th = theta + (n*NJ + tid)*3;
        float x = th[0], y = th[1], z = th[2];
        float nrm = sqrtf(x*x + y*y + z*z);
        float t = fmaxf(nrm, 1.1754944e-38f);
        float inv = 1.0f / t;
        float rx = x*inv, ry = y*inv, rz = z*inv;
        float c = cosf(t), s = sinf(t), oc = 1.0f - c;
        Rsm[tid][0] = c + oc*rx*rx;      Rsm[tid][1] = oc*rx*ry - s*rz;  Rsm[tid][2] = oc*rx*rz + s*ry;
        Rsm[tid][3] = oc*ry*rx + s*rz;   Rsm[tid][4] = c + oc*ry*ry;     Rsm[tid][5] = oc*ry*rz - s*rx;
        Rsm[tid][6] = oc*rz*rx - s*ry;   Rsm[tid][7] = oc*rz*ry + s*rx;  Rsm[tid][8] = c + oc*rz*rz;
    } else if (tid < 2*NJ) {        // lanes 24-47: J rows (3 dots of 11 each)
        int j = tid - NJ;
        #pragma unroll
        for (int c = 0; c < 3; ++c) {
            float s = JB[(j*3+c)*11 + 0];
            #pragma unroll
            for (int b = 0; b < NB; ++b) s += JB[(j*3+c)*11 + 1 + b] * beta[n*NB + b];
            Jsm[j][c] = s;
        }
    }
    __syncthreads();

    if (tid < 12) {
        int a = tid >> 2, b = tid & 3;
        Gsm[0][a*4+b] = (b < 3) ? Rsm[0][a*3+b] : Jsm[0][a];
    }
    __syncthreads();
    for (int i = 1; i < NJ; ++i) {
        if (tid < 12) {
            int a = tid >> 2, b = tid & 3;
            int p = PAR[i];
            float acc = (b == 3) ? Gsm[p][a*4+3] : 0.0f;
            #pragma unroll
            for (int k = 0; k < 3; ++k) {
                float aval = (b < 3) ? Rsm[i][k*3+b] : (Jsm[i][k] - Jsm[p][k]);
                acc += Gsm[p][a*4+k] * aval;
            }
            Gsm[i][a*4+b] = acc;
        }
        __syncthreads();
    }
    if (tid < NJ) {   // t' = t - R.J + trans (trans folds: sum_j w = 1)
        int j = tid;
        #pragma unroll
        for (int a = 0; a < 3; ++a) {
            float t3 = Gsm[j][a*4+3]
                     - (Gsm[j][a*4+0]*Jsm[j][0] + Gsm[j][a*4+1]*Jsm[j][1] + Gsm[j][a*4+2]*Jsm[j][2])
                     + trans[n*3 + a];
            Gsm[j][a*4+3] = t3;
        }
    }
    __syncthreads();
    // Gt[n][e=0..15][j=0..31] bf16 zero-padded
    unsigned short* gt = Gt + n*512;
    for (int idx = tid; idx < 512; idx += 64) {
        int e = idx >> 5, j = idx & 31;
        float val = (e < 12 && j < NJ) ? Gsm[j][e] : 0.0f;
        gt[idx] = f2bf(val);
    }
    // A-row, K-tiled layout [k/32][n][32]
    for (int k = tid; k < KP; k += 64) {
        float val;
        if (k < NB) val = beta[n*NB + k];
        else if (k < KC) {
            int p = k - NB; int jj = p/9 + 1; int rr = p%9;
            val = Rsm[jj][rr] - ((rr==0 || rr==4 || rr==8) ? 1.0f : 0.0f);
        } else if (k == KC) val = 1.0f;
        else val = 0.0f;
        Arow[((size_t)(k >> 5)*NBATCH + n)*32 + (k & 31)] = f2bf(val);
    }
}

// ---------------- K_main: persistent n-loop; hoisted+pinned B/W frags; MFMA GEMM1+GEMM2 ----------------
__global__ __launch_bounds__(256) void k_main(const unsigned short* __restrict__ Arow,
                                              const unsigned short* __restrict__ Bmat,
                                              const unsigned short* __restrict__ Gt,
                                              const float* __restrict__ weights,
                                              float* __restrict__ verts) {
    __shared__ __attribute__((aligned(16))) unsigned short vhsm[BN*VST4];   // 16640 B

    int tid = threadIdx.x;
    int wv = tid >> 6, lane = tid & 63;
    int l15 = lane & 15, jg = lane >> 4;
    int ns = blockIdx.x, vb = blockIdx.y;
    int v0 = vb * BV, vc0 = v0 * 3;
    int vcw0 = vc0 + wv*48;             // this wave's 48 vc columns

    // ---- hoist B fragments (7 ks x 3 ct), pinned against rematerialization ----
    bh8 bfr[7][3];
    #pragma unroll
    for (int ks = 0; ks < 7; ++ks)
        #pragma unroll
        for (int ct = 0; ct < 3; ++ct)
            bfr[ks][ct] = *(const bh8*)(Bmat + ((size_t)ks*VCP + vcw0 + ct*16 + l15)*32 + jg*8);
    #pragma unroll
    for (int ks = 0; ks < 7; ++ks)
        #pragma unroll
        for (int ct = 0; ct < 3; ++ct)
            asm volatile("" : "+v"(bfr[ks][ct]));

    // ---- W fragments (B-operand of GEMM2), pinned ----
    bh8 wfrag[4];
    #pragma unroll
    for (int mt = 0; mt < 4; ++mt) {
        int vr = v0 + mt*16 + l15;
        bh8 f = {0,0,0,0,0,0,0,0};
        if (jg < 3 && vr < V) {
            const float4* wp = (const float4*)(weights + (size_t)vr*NJ + jg*8);
            float4 w0 = wp[0], w1 = wp[1];
            f[0]=(short)f2bf(w0.x); f[1]=(short)f2bf(w0.y); f[2]=(short)f2bf(w0.z); f[3]=(short)f2bf(w0.w);
            f[4]=(short)f2bf(w1.x); f[5]=(short)f2bf(w1.y); f[6]=(short)f2bf(w1.z); f[7]=(short)f2bf(w1.w);
        }
        wfrag[mt] = f;
    }
    #pragma unroll
    for (int mt = 0; mt < 4; ++mt) asm volatile("" : "+v"(wfrag[mt]));

    // per-lane spill column mapping (vc -> padded-4 col), constant across iters
    int c4[3];
    #pragma unroll
    for (int ct = 0; ct < 3; ++ct) {
        int vcw = wv*48 + ct*16 + l15;          // [0,192)
        c4[ct] = (vcw/3)*4 + vcw%3;
    }
    int tri = (((lane % 3)*16) + lane/3) * 4;   // bpermute byte index for output transpose

    #pragma unroll 1
    for (int it = 0; it < ITERS; ++it) {
        int n0 = (ns*ITERS + it) * BN;

        // ---- A fragments for this n-tile (batched issue, one wait) ----
        bh8 af[7][2];
        #pragma unroll
        for (int ks = 0; ks < 7; ++ks)
            #pragma unroll
            for (int mt = 0; mt < 2; ++mt)
                af[ks][mt] = *(const bh8*)(Arow + ((size_t)ks*NBATCH + n0 + mt*16 + l15)*32 + jg*8);
        #pragma unroll
        for (int ks = 0; ks < 7; ++ks)
            #pragma unroll
            for (int mt = 0; mt < 2; ++mt)
                asm volatile("" : "+v"(af[ks][mt]));

        // ---- GEMM1: vh = Arow . Bmat^T (all operands in registers) ----
        f32x4 acc[2][3] = {};
        #pragma unroll
        for (int ks = 0; ks < 7; ++ks)
            #pragma unroll
            for (int mt = 0; mt < 2; ++mt)
                #pragma unroll
                for (int ct = 0; ct < 3; ++ct)
                    acc[mt][ct] = __builtin_amdgcn_mfma_f32_16x16x32_bf16(af[ks][mt], bfr[ks][ct], acc[mt][ct], 0, 0, 0);

        __syncthreads();    // prev iter's GEMM2 reads done
        // spill (bf16, padded-4): row = n_local, col = v*4+b
        #pragma unroll
        for (int mt = 0; mt < 2; ++mt)
            #pragma unroll
            for (int ct = 0; ct < 3; ++ct)
                #pragma unroll
                for (int r = 0; r < 4; ++r)
                    vhsm[(mt*16 + jg*4 + r)*VST4 + c4[ct]] = f2bf(acc[mt][ct][r]);
        __syncthreads();

        // ---- GEMM2 + apply + transpose + NT store ----
        const unsigned short* gbase = Gt + ((size_t)(n0 + wv*8))*512 + l15*32 + jg*8;
        bh8 gcur = *(const bh8*)gbase;
        #pragma unroll
        for (int nl = 0; nl < 8; ++nl) {
            bh8 gnxt = gcur;
            if (nl < 7) gnxt = *(const bh8*)(gbase + (nl+1)*512);
            int n_loc = wv*8 + nl;
            #pragma unroll
            for (int mt = 0; mt < 4; ++mt) {
                f32x4 z = {0.f, 0.f, 0.f, 0.f};
                f32x4 t = __builtin_amdgcn_mfma_f32_16x16x32_bf16(gcur, wfrag[mt], z, 0, 0, 0);
                u16x4 vh4 = *(const u16x4*)&vhsm[n_loc*VST4 + (mt*16 + l15)*4];
                float p = t[0]*bf2f(vh4[0]) + t[1]*bf2f(vh4[1]) + t[2]*bf2f(vh4[2]) + t[3];
                float pp = __int_as_float(__builtin_amdgcn_ds_bpermute(tri, __float_as_int(p)));
                int col = vc0 + mt*48 + lane;
                if (lane < 48 && col < VC)
                    __builtin_nontemporal_store(pp, verts + (size_t)(n0 + n_loc)*VC + col);
            }
            gcur = gnxt;
        }
    }
}

// ---------------- K_joints: MFMA GEMM  jpart[ks][n][kc] = verts[n,:] x Jbig[kc,:]^T (K-slice) ----------------
__global__ __launch_bounds__(256) void k_joints(const float* __restrict__ verts,
                                                const unsigned short* __restrict__ Jbig,
                                                float* __restrict__ jpart) {
    int tid = threadIdx.x;
    int lane = tid & 63, wv = tid >> 6;
    int l15 = lane & 15, jg = lane >> 4;
    int nt = blockIdx.x, ks = blockIdx.y;
    int n0 = nt * 32;
    int s0 = ks * KCHUNK;
    int s1 = min(KSTEPS, s0 + KCHUNK);

    const unsigned short* jb = Jbig + (size_t)(wv*16 + l15)*VCP + jg*8;
    const float* va = verts + (size_t)(n0 + l15)*VC + jg*8;
    const float* vb = verts + (size_t)(n0 + 16 + l15)*VC + jg*8;

    f32x4 acc[2] = {};
    bh8 bcur = *(const bh8*)(jb + (size_t)s0*32);
    bh8 a0c = ld_cvt8(va + s0*32);
    bh8 a1c = ld_cvt8(vb + s0*32);
    for (int s = s0; s < s1; ++s) {
        bh8 bn = bcur, a0n = a0c, a1n = a1c;
        if (s + 1 < s1) {
            bn  = *(const bh8*)(jb + (size_t)(s+1)*32);
            a0n = ld_cvt8(va + (s+1)*32);
            a1n = ld_cvt8(vb + (s+1)*32);
        }
        acc[0] = __builtin_amdgcn_mfma_f32_16x16x32_bf16(a0c, bcur, acc[0], 0, 0, 0);
        acc[1] = __builtin_amdgcn_mfma_f32_16x16x32_bf16(a1c, bcur, acc[1], 0, 0, 0);
        bcur = bn; a0c = a0n; a1c = a1n;
    }
    // D: col=lane&15 (kc within wave), row=(lane>>4)*4+r (n within 16-tile)
    float* jp = jpart + ((size_t)ks*NBATCH + n0)*64 + wv*16 + l15;
    #pragma unroll
    for (int mt = 0; mt < 2; ++mt)
        #pragma unroll
        for (int r = 0; r < 4; ++r)
            jp[(size_t)(mt*16 + jg*4 + r)*64] = acc[mt][r];
}

// ---------------- K_jred: joints[n, i] = sum_ks jpart[ks][n][i] ----------------
__global__ __launch_bounds__(256) void k_jred(const float* __restrict__ jpart,
                                              float* __restrict__ joints) {
    int idx = blockIdx.x*256 + threadIdx.x;
    if (idx >= NBATCH*NK*3) return;
    int n = idx / (NK*3), i = idx - n*(NK*3);
    float s = 0.f;
    #pragma unroll
    for (int ks = 0; ks < KSP; ++ks)
        s += jpart[((size_t)ks*NBATCH + n)*64 + i];
    joints[idx] = s;
}

extern "C" void kernel_launch(void* const* d_in, const int* in_sizes, int n_in,
                              void* d_out, int out_size, void* d_ws, size_t ws_size,
                              hipStream_t stream) {
    const float* beta  = (const float*)d_in[0];
    const float* theta = (const float*)d_in[1];
    const float* trans = (const float*)d_in[2];
    const float* sdirs = (const float*)d_in[3];
    const float* vtmpl = (const float*)d_in[4];
    const float* jregJ = (const float*)d_in[5];
    const float* pdirs = (const float*)d_in[6];
    const float* wgts  = (const float*)d_in[7];
    const float* jregK = (const float*)d_in[8];

    float* verts  = (float*)d_out;
    float* joints = verts + (size_t)NBATCH * VC;

    char* ws = (char*)d_ws;
    float*          JB    = (float*)ws;                                      // 4096 B (zeroed)
    unsigned short* Arow  = (unsigned short*)(ws + 4096);                    // 917504 B
    unsigned short* Gt    = (unsigned short*)(ws + 4096 + 917504);           // 2097152 B
    unsigned short* Bmat  = (unsigned short*)(ws + 4096 + 917504 + 2097152); // 9289728 B
    unsigned short* Jbig  = (unsigned short*)(ws + 4096 + 917504 + 2097152 + 9289728); // 64*VCP*2 = 2654208
    float*          jpart = (float*)(ws + 4096 + 917504 + 2097152 + 9289728 + 2654208); // 16*2048*64*4 = 8388608

    hipMemsetAsync(JB, 0, 4096, stream);

    k_prep <<<792 + 18144 + 5184, 256, 0, stream>>>(jregJ, vtmpl, sdirs, pdirs, jregK, JB, Bmat, Jbig);
    k_pern <<<NBATCH, 64, 0, stream>>>(beta, theta, trans, JB, Arow, Gt);
    dim3 g4(NSPLIT, (V + BV - 1)/BV);   // (16, 108)
    k_main <<<g4, 256, 0, stream>>>(Arow, Bmat, Gt, wgts, verts);
    dim3 g5(NBATCH/BN, KSP);            // (64, 16)
    k_joints<<<g5, 256, 0, stream>>>(verts, Jbig, jpart);
    k_jred <<<(NBATCH*NK*3 + 255)/256, 256, 0, stream>>>(jpart, joints);
}

// Round 7
// 190.902 us; speedup vs baseline: 1.6568x; 1.2448x over previous
//
#include <hip/hip_runtime.h>

#define V      6890
#define NJ     24
#define NB     10
#define NP     207
#define NK     19
#define NBATCH 2048
#define KP     224      // padded K: 10 beta + 207 lrotmin + 1 const + 6 zero
#define KC     217      // constant-1 column (-> v_template)
#define VC     (V*3)    // 20670
#define VCP    20736    // padded VC (= 108*64*3)
#define BN     32       // n-tile
#define BV     64       // v-tile per block
#define NSPLIT 16
#define ITERS  (NBATCH/BN/NSPLIT)   // 4 n-tiles per block
#define VST4   260      // vhsm row stride in shorts (520 B: 8B-aligned, jg-groups 8 banks apart)
#define VSEG   1723     // ceil(V/4) for V-splits (k_prep JB dots)
#define KSTEPS 648      // VCP/32
#define JSP    18       // joints GEMM K-split (18 slices x 9 chunks x 4 steps = 648)
#define JCH    9        // chunks per slice; chunk = 4 k-steps = 128 floats

using bh8   = __attribute__((ext_vector_type(8))) short;          // 8 x bf16
using u16x4 = __attribute__((ext_vector_type(4))) unsigned short;
using f32x4 = __attribute__((ext_vector_type(4))) float;

__constant__ int PAR[NJ] = {-1,0,0,0,1,2,3,4,5,6,7,8,9,9,9,12,13,14,16,17,18,19,20,21};

__device__ __forceinline__ unsigned short f2bf(float f) {
    unsigned int u = __float_as_uint(f);
    u += 0x7FFFu + ((u >> 16) & 1u);   // RNE; no NaNs in this data
    return (unsigned short)(u >> 16);
}
__device__ __forceinline__ float bf2f(unsigned short h) {
    return __uint_as_float((unsigned int)h << 16);
}

// ---------------- K_prep: fused [k_jb(V-split, atomic) | k_bmat(K-tiled) | JbigT(K-tiled)] ----------------
__global__ __launch_bounds__(256) void k_prep(const float* __restrict__ Jreg,
                                              const float* __restrict__ vtmpl,
                                              const float* __restrict__ sdirs,
                                              const float* __restrict__ pdirs,
                                              const float* __restrict__ jreg,
                                              float* __restrict__ JB,
                                              unsigned short* __restrict__ Bmat,
                                              unsigned short* __restrict__ JbigT) {
    int blk = blockIdx.x, tid = threadIdx.x;
    if (blk < 792) {                       // JB partial dots, 4-way V-split, atomic accumulate
        int vs = blk & 3, og = blk >> 2;
        int o = og*4 + (tid >> 6);         // o in [0,792) = 24*33
        int lane = tid & 63;
        int j = o/33, t = o%33, c = t/11, m = t%11;
        int lo = vs*VSEG + lane, hi = min(V, vs*VSEG + VSEG);
        const float* jr = Jreg + j*V;
        float s = 0.f;
        if (m == 0) { for (int v = lo; v < hi; v += 64) s += jr[v] * vtmpl[v*3 + c]; }
        else        { for (int v = lo; v < hi; v += 64) s += jr[v] * sdirs[(v*3 + c)*NB + (m-1)]; }
        #pragma unroll
        for (int d = 1; d < 64; d <<= 1) s += __shfl_xor(s, d);
        if (lane == 0) atomicAdd(&JB[(j*3 + c)*11 + m], s);
    } else if (blk < 792 + 18144) {        // Bmat, K-tiled layout [k/32][vc][32]
        int gid = (blk - 792)*256 + tid;   // covers VCP*KP
        int vc = gid / KP, k = gid - vc*KP;
        float val;
        if (vc >= VC)     val = 0.f;
        else if (k < NB)  val = sdirs[vc*NB + k];
        else if (k < KC)  val = pdirs[vc*NP + (k - NB)];
        else if (k == KC) val = vtmpl[vc];
        else              val = 0.f;
        Bmat[((size_t)(k >> 5)*VCP + vc)*32 + (k & 31)] = f2bf(val);
    } else {                               // JbigT[vc/32][kc][vc%32] bf16: delta(kc%3,vc%3)*jreg[vc/3][kc/3]
        int gid = (blk - 792 - 18144)*256 + tid;   // covers 64*VCP
        int kc = gid / VCP, vc = gid - kc*VCP;
        float val = 0.f;
        if (kc < NK*3 && vc < VC && (kc % 3) == (vc % 3))
            val = jreg[(vc/3)*NK + (kc/3)];
        JbigT[((size_t)(vc >> 5)*64 + kc)*32 + (vc & 31)] = f2bf(val);
    }
}

// ---------------- K_pern: one WAVE per n (64-thread block; barriers ~free) ----------------
__global__ __launch_bounds__(64) void k_pern(const float* __restrict__ beta,
                                             const float* __restrict__ theta,
                                             const float* __restrict__ trans,
                                             const float* __restrict__ JB,
                                             unsigned short* __restrict__ Arow,
                                             unsigned short* __restrict__ Gt) {
    int n = blockIdx.x, tid = threadIdx.x;
    __shared__ float Rsm[NJ][9];
    __shared__ float Jsm[NJ][3];
    __shared__ float Gsm[NJ][12];   // 3x4, e = a*4+b

    if (tid < NJ) {                 // lanes 0-23: rodrigues
        const float* th = theta + (n*NJ + tid)*3;
        float x = th[0], y = th[1], z = th[2];
        float nrm = sqrtf(x*x + y*y + z*z);
        float t = fmaxf(nrm, 1.1754944e-38f);
        float inv = 1.0f / t;
        float rx = x*inv, ry = y*inv, rz = z*inv;
        float c = cosf(t), s = sinf(t), oc = 1.0f - c;
        Rsm[tid][0] = c + oc*rx*rx;      Rsm[tid][1] = oc*rx*ry - s*rz;  Rsm[tid][2] = oc*rx*rz + s*ry;
        Rsm[tid][3] = oc*ry*rx + s*rz;   Rsm[tid][4] = c + oc*ry*ry;     Rsm[tid][5] = oc*ry*rz - s*rx;
        Rsm[tid][6] = oc*rz*rx - s*ry;   Rsm[tid][7] = oc*rz*ry + s*rx;  Rsm[tid][8] = c + oc*rz*rz;
    } else if (tid < 2*NJ) {        // lanes 24-47: J rows (3 dots of 11 each)
        int j = tid - NJ;
        #pragma unroll
        for (int c = 0; c < 3; ++c) {
            float s = JB[(j*3+c)*11 + 0];
            #pragma unroll
            for (int b = 0; b < NB; ++b) s += JB[(j*3+c)*11 + 1 + b] * beta[n*NB + b];
            Jsm[j][c] = s;
        }
    }
    __syncthreads();

    if (tid < 12) {
        int a = tid >> 2, b = tid & 3;
        Gsm[0][a*4+b] = (b < 3) ? Rsm[0][a*3+b] : Jsm[0][a];
    }
    __syncthreads();
    for (int i = 1; i < NJ; ++i) {
        if (tid < 12) {
            int a = tid >> 2, b = tid & 3;
            int p = PAR[i];
            float acc = (b == 3) ? Gsm[p][a*4+3] : 0.0f;
            #pragma unroll
            for (int k = 0; k < 3; ++k) {
                float aval = (b < 3) ? Rsm[i][k*3+b] : (Jsm[i][k] - Jsm[p][k]);
                acc += Gsm[p][a*4+k] * aval;
            }
            Gsm[i][a*4+b] = acc;
        }
        __syncthreads();
    }
    if (tid < NJ) {   // t' = t - R.J + trans (trans folds: sum_j w = 1)
        int j = tid;
        #pragma unroll
        for (int a = 0; a < 3; ++a) {
            float t3 = Gsm[j][a*4+3]
                     - (Gsm[j][a*4+0]*Jsm[j][0] + Gsm[j][a*4+1]*Jsm[j][1] + Gsm[j][a*4+2]*Jsm[j][2])
                     + trans[n*3 + a];
            Gsm[j][a*4+3] = t3;
        }
    }
    __syncthreads();
    // Gt[n][e=0..15][j=0..31] bf16 zero-padded
    unsigned short* gt = Gt + n*512;
    for (int idx = tid; idx < 512; idx += 64) {
        int e = idx >> 5, j = idx & 31;
        float val = (e < 12 && j < NJ) ? Gsm[j][e] : 0.0f;
        gt[idx] = f2bf(val);
    }
    // A-row, K-tiled layout [k/32][n][32]
    for (int k = tid; k < KP; k += 64) {
        float val;
        if (k < NB) val = beta[n*NB + k];
        else if (k < KC) {
            int p = k - NB; int jj = p/9 + 1; int rr = p%9;
            val = Rsm[jj][rr] - ((rr==0 || rr==4 || rr==8) ? 1.0f : 0.0f);
        } else if (k == KC) val = 1.0f;
        else val = 0.0f;
        Arow[((size_t)(k >> 5)*NBATCH + n)*32 + (k & 31)] = f2bf(val);
    }
}

// ---------------- K_main: persistent n-loop; hoisted+pinned B/W frags; MFMA GEMM1+GEMM2 ----------------
__global__ __launch_bounds__(256) void k_main(const unsigned short* __restrict__ Arow,
                                              const unsigned short* __restrict__ Bmat,
                                              const unsigned short* __restrict__ Gt,
                                              const float* __restrict__ weights,
                                              float* __restrict__ verts) {
    __shared__ __attribute__((aligned(16))) unsigned short vhsm[BN*VST4];   // 16640 B

    int tid = threadIdx.x;
    int wv = tid >> 6, lane = tid & 63;
    int l15 = lane & 15, jg = lane >> 4;
    int ns = blockIdx.x, vb = blockIdx.y;
    int v0 = vb * BV, vc0 = v0 * 3;
    int vcw0 = vc0 + wv*48;             // this wave's 48 vc columns

    // ---- hoist B fragments (7 ks x 3 ct), pinned against rematerialization ----
    bh8 bfr[7][3];
    #pragma unroll
    for (int ks = 0; ks < 7; ++ks)
        #pragma unroll
        for (int ct = 0; ct < 3; ++ct)
            bfr[ks][ct] = *(const bh8*)(Bmat + ((size_t)ks*VCP + vcw0 + ct*16 + l15)*32 + jg*8);
    #pragma unroll
    for (int ks = 0; ks < 7; ++ks)
        #pragma unroll
        for (int ct = 0; ct < 3; ++ct)
            asm volatile("" : "+v"(bfr[ks][ct]));

    // ---- W fragments (B-operand of GEMM2), pinned ----
    bh8 wfrag[4];
    #pragma unroll
    for (int mt = 0; mt < 4; ++mt) {
        int vr = v0 + mt*16 + l15;
        bh8 f = {0,0,0,0,0,0,0,0};
        if (jg < 3 && vr < V) {
            const float4* wp = (const float4*)(weights + (size_t)vr*NJ + jg*8);
            float4 w0 = wp[0], w1 = wp[1];
            f[0]=(short)f2bf(w0.x); f[1]=(short)f2bf(w0.y); f[2]=(short)f2bf(w0.z); f[3]=(short)f2bf(w0.w);
            f[4]=(short)f2bf(w1.x); f[5]=(short)f2bf(w1.y); f[6]=(short)f2bf(w1.z); f[7]=(short)f2bf(w1.w);
        }
        wfrag[mt] = f;
    }
    #pragma unroll
    for (int mt = 0; mt < 4; ++mt) asm volatile("" : "+v"(wfrag[mt]));

    // per-lane spill column mapping (vc -> padded-4 col), constant across iters
    int c4[3];
    #pragma unroll
    for (int ct = 0; ct < 3; ++ct) {
        int vcw = wv*48 + ct*16 + l15;          // [0,192)
        c4[ct] = (vcw/3)*4 + vcw%3;
    }
    int tri = (((lane % 3)*16) + lane/3) * 4;   // bpermute byte index for output transpose

    #pragma unroll 1
    for (int it = 0; it < ITERS; ++it) {
        int n0 = (ns*ITERS + it) * BN;

        // ---- A fragments for this n-tile (batched issue, one wait) ----
        bh8 af[7][2];
        #pragma unroll
        for (int ks = 0; ks < 7; ++ks)
            #pragma unroll
            for (int mt = 0; mt < 2; ++mt)
                af[ks][mt] = *(const bh8*)(Arow + ((size_t)ks*NBATCH + n0 + mt*16 + l15)*32 + jg*8);
        #pragma unroll
        for (int ks = 0; ks < 7; ++ks)
            #pragma unroll
            for (int mt = 0; mt < 2; ++mt)
                asm volatile("" : "+v"(af[ks][mt]));

        // ---- GEMM1: vh = Arow . Bmat^T (all operands in registers) ----
        f32x4 acc[2][3] = {};
        #pragma unroll
        for (int ks = 0; ks < 7; ++ks)
            #pragma unroll
            for (int mt = 0; mt < 2; ++mt)
                #pragma unroll
                for (int ct = 0; ct < 3; ++ct)
                    acc[mt][ct] = __builtin_amdgcn_mfma_f32_16x16x32_bf16(af[ks][mt], bfr[ks][ct], acc[mt][ct], 0, 0, 0);

        __syncthreads();    // prev iter's GEMM2 reads done
        // spill (bf16, padded-4): row = n_local, col = v*4+b
        #pragma unroll
        for (int mt = 0; mt < 2; ++mt)
            #pragma unroll
            for (int ct = 0; ct < 3; ++ct)
                #pragma unroll
                for (int r = 0; r < 4; ++r)
                    vhsm[(mt*16 + jg*4 + r)*VST4 + c4[ct]] = f2bf(acc[mt][ct][r]);
        __syncthreads();

        // ---- GEMM2 + apply + transpose + NT store ----
        const unsigned short* gbase = Gt + ((size_t)(n0 + wv*8))*512 + l15*32 + jg*8;
        bh8 gcur = *(const bh8*)gbase;
        #pragma unroll
        for (int nl = 0; nl < 8; ++nl) {
            bh8 gnxt = gcur;
            if (nl < 7) gnxt = *(const bh8*)(gbase + (nl+1)*512);
            int n_loc = wv*8 + nl;
            #pragma unroll
            for (int mt = 0; mt < 4; ++mt) {
                f32x4 z = {0.f, 0.f, 0.f, 0.f};
                f32x4 t = __builtin_amdgcn_mfma_f32_16x16x32_bf16(gcur, wfrag[mt], z, 0, 0, 0);
                u16x4 vh4 = *(const u16x4*)&vhsm[n_loc*VST4 + (mt*16 + l15)*4];
                float p = t[0]*bf2f(vh4[0]) + t[1]*bf2f(vh4[1]) + t[2]*bf2f(vh4[2]) + t[3];
                float pp = __int_as_float(__builtin_amdgcn_ds_bpermute(tri, __float_as_int(p)));
                int col = vc0 + mt*48 + lane;
                if (lane < 48 && col < VC)
                    __builtin_nontemporal_store(pp, verts + (size_t)(n0 + n_loc)*VC + col);
            }
            gcur = gnxt;
        }
    }
}

// ---------------- K_joints: LDS-staged MFMA GEMM  jpart[ks][n][kc] += verts x JbigT ----------------
// Stage 32n x 128 floats -> LDS bf16 (coalesced float2 loads, XOR-swizzled), then
// fragment reads from LDS (2-way, free). Next chunk's loads issued before MFMAs (T14).
__global__ __launch_bounds__(256) void k_joints(const float* __restrict__ verts,
                                                const unsigned short* __restrict__ JbigT,
                                                float* __restrict__ jpart) {
    __shared__ __attribute__((aligned(16))) unsigned short vt[32*128];   // 8 KB

    int tid = threadIdx.x;
    int lane = tid & 63, wv = tid >> 6;
    int l15 = lane & 15, jg = lane >> 4;
    int nt = blockIdx.x, ks = blockIdx.y;
    int n0 = nt * 32;
    int step0 = ks * (JCH*4);          // 36 k-steps per slice

    int row[4], c4[4];
    #pragma unroll
    for (int i = 0; i < 4; ++i) {
        int idx = i*256 + tid;         // 1024 16B-units = 32 rows x 32
        row[i] = idx >> 5; c4[i] = idx & 31;
    }

    float2 rg[8];
    auto issue = [&](int ch) {         // coalesced: consecutive lanes -> consecutive 8B
        int k0f = (step0 + ch*4) * 32;
        #pragma unroll
        for (int i = 0; i < 4; ++i) {
            const float* p = verts + (size_t)(n0 + row[i])*VC + k0f + c4[i]*4;
            rg[2*i+0] = *(const float2*)(p);
            rg[2*i+1] = *(const float2*)(p+2);
        }
    };

    issue(0);
    f32x4 acc[2] = {};
    #pragma unroll 1
    for (int ch = 0; ch < JCH; ++ch) {
        __syncthreads();               // prev chunk's fragment reads done
        #pragma unroll
        for (int i = 0; i < 4; ++i) {
            u16x4 w;
            w[0] = f2bf(rg[2*i].x); w[1] = f2bf(rg[2*i].y);
            w[2] = f2bf(rg[2*i+1].x); w[3] = f2bf(rg[2*i+1].y);
            int sidx = (row[i]*128 + c4[i]*4) ^ ((row[i] & 7) << 3);
            *(u16x4*)&vt[sidx] = w;
        }
        __syncthreads();
        if (ch + 1 < JCH) issue(ch + 1);   // overlap next-stage loads with MFMAs
        #pragma unroll
        for (int kk = 0; kk < 4; ++kk) {
            int r0 = l15, r1 = 16 + l15;
            bh8 a0 = *(const bh8*)&vt[(r0*128 + kk*32 + jg*8) ^ ((r0 & 7) << 3)];
            bh8 a1 = *(const bh8*)&vt[(r1*128 + kk*32 + jg*8) ^ ((r1 & 7) << 3)];
            bh8 b  = *(const bh8*)(JbigT + ((size_t)(step0 + ch*4 + kk)*64 + wv*16 + l15)*32 + jg*8);
            acc[0] = __builtin_amdgcn_mfma_f32_16x16x32_bf16(a0, b, acc[0], 0, 0, 0);
            acc[1] = __builtin_amdgcn_mfma_f32_16x16x32_bf16(a1, b, acc[1], 0, 0, 0);
        }
    }
    // D: col=lane&15 (kc within wave), row=(lane>>4)*4+r (n within 16-tile)
    float* jp = jpart + ((size_t)ks*NBATCH + n0)*64 + wv*16 + l15;
    #pragma unroll
    for (int mt = 0; mt < 2; ++mt)
        #pragma unroll
        for (int r = 0; r < 4; ++r)
            jp[(size_t)(mt*16 + jg*4 + r)*64] = acc[mt][r];
}

// ---------------- K_jred: joints[n, i] = sum_ks jpart[ks][n][i] ----------------
__global__ __launch_bounds__(256) void k_jred(const float* __restrict__ jpart,
                                              float* __restrict__ joints) {
    int idx = blockIdx.x*256 + threadIdx.x;
    if (idx >= NBATCH*NK*3) return;
    int n = idx / (NK*3), i = idx - n*(NK*3);
    float s = 0.f;
    #pragma unroll
    for (int ks = 0; ks < JSP; ++ks)
        s += jpart[((size_t)ks*NBATCH + n)*64 + i];
    joints[idx] = s;
}

extern "C" void kernel_launch(void* const* d_in, const int* in_sizes, int n_in,
                              void* d_out, int out_size, void* d_ws, size_t ws_size,
                              hipStream_t stream) {
    const float* beta  = (const float*)d_in[0];
    const float* theta = (const float*)d_in[1];
    const float* trans = (const float*)d_in[2];
    const float* sdirs = (const float*)d_in[3];
    const float* vtmpl = (const float*)d_in[4];
    const float* jregJ = (const float*)d_in[5];
    const float* pdirs = (const float*)d_in[6];
    const float* wgts  = (const float*)d_in[7];
    const float* jregK = (const float*)d_in[8];

    float* verts  = (float*)d_out;
    float* joints = verts + (size_t)NBATCH * VC;

    char* ws = (char*)d_ws;
    float*          JB    = (float*)ws;                                      // 4096 B (zeroed)
    unsigned short* Arow  = (unsigned short*)(ws + 4096);                    // 917504 B
    unsigned short* Gt    = (unsigned short*)(ws + 4096 + 917504);           // 2097152 B
    unsigned short* Bmat  = (unsigned short*)(ws + 4096 + 917504 + 2097152); // 9289728 B
    unsigned short* JbigT = (unsigned short*)(ws + 4096 + 917504 + 2097152 + 9289728); // 648*64*32*2 = 2654208
    float*          jpart = (float*)(ws + 4096 + 917504 + 2097152 + 9289728 + 2654208); // 18*2048*64*4 = 9437184

    hipMemsetAsync(JB, 0, 4096, stream);

    k_prep <<<792 + 18144 + 5184, 256, 0, stream>>>(jregJ, vtmpl, sdirs, pdirs, jregK, JB, Bmat, JbigT);
    k_pern <<<NBATCH, 64, 0, stream>>>(beta, theta, trans, JB, Arow, Gt);
    dim3 g4(NSPLIT, (V + BV - 1)/BV);   // (16, 108)
    k_main <<<g4, 256, 0, stream>>>(Arow, Bmat, Gt, wgts, verts);
    dim3 g5(NBATCH/BN, JSP);            // (64, 18)
    k_joints<<<g5, 256, 0, stream>>>(verts, JbigT, jpart);
    k_jred <<<(NBATCH*NK*3 + 255)/256, 256, 0, stream>>>(jpart, joints);
}

// Round 8
// 177.486 us; speedup vs baseline: 1.7821x; 1.0756x over previous
//
#include <hip/hip_runtime.h>

#define V      6890
#define NJ     24
#define NB     10
#define NP     207
#define NK     19
#define NBATCH 2048
#define KP     224      // padded K: 10 beta + 207 lrotmin + 1 const + 6 zero
#define KC     217      // constant-1 column (-> v_template)
#define VC     (V*3)    // 20670
#define VCP    20736    // padded VC (= 108*64*3)
#define BN     32       // n-tile
#define BV     64       // v-tile per block
#define NSPLIT 16
#define ITERS  (NBATCH/BN/NSPLIT)   // 4 n-tiles per block
#define VST4   260      // vhsm row stride in shorts (520 B: 8B-aligned, jg-groups 8 banks apart)
#define VSEG   1723     // ceil(V/4) for V-splits (k_prep JB dots)
#define KSTEPS 648      // VCP/32
#define JSP    18       // joints GEMM K-split (18 slices x 9 chunks x 4 steps = 648)
#define JCH    9        // chunks per slice; chunk = 4 k-steps = 128 floats

using bh8   = __attribute__((ext_vector_type(8))) short;          // 8 x bf16
using u16x4 = __attribute__((ext_vector_type(4))) unsigned short;
using f32x4 = __attribute__((ext_vector_type(4))) float;

__constant__ int PAR[NJ] = {-1,0,0,0,1,2,3,4,5,6,7,8,9,9,9,12,13,14,16,17,18,19,20,21};

__device__ __forceinline__ unsigned short f2bf(float f) {
    unsigned int u = __float_as_uint(f);
    u += 0x7FFFu + ((u >> 16) & 1u);   // RNE; no NaNs in this data
    return (unsigned short)(u >> 16);
}
__device__ __forceinline__ float bf2f(unsigned short h) {
    return __uint_as_float((unsigned int)h << 16);
}

// ---------------- K_prep: fused [k_jb(V-split, atomic) | k_bmat(K-tiled) | JbigT(K-tiled)] ----------------
__global__ __launch_bounds__(256) void k_prep(const float* __restrict__ Jreg,
                                              const float* __restrict__ vtmpl,
                                              const float* __restrict__ sdirs,
                                              const float* __restrict__ pdirs,
                                              const float* __restrict__ jreg,
                                              float* __restrict__ JB,
                                              unsigned short* __restrict__ Bmat,
                                              unsigned short* __restrict__ JbigT) {
    int blk = blockIdx.x, tid = threadIdx.x;
    if (blk < 792) {                       // JB partial dots, 4-way V-split, atomic accumulate
        int vs = blk & 3, og = blk >> 2;
        int o = og*4 + (tid >> 6);         // o in [0,792) = 24*33
        int lane = tid & 63;
        int j = o/33, t = o%33, c = t/11, m = t%11;
        int lo = vs*VSEG + lane, hi = min(V, vs*VSEG + VSEG);
        const float* jr = Jreg + j*V;
        float s = 0.f;
        if (m == 0) { for (int v = lo; v < hi; v += 64) s += jr[v] * vtmpl[v*3 + c]; }
        else        { for (int v = lo; v < hi; v += 64) s += jr[v] * sdirs[(v*3 + c)*NB + (m-1)]; }
        #pragma unroll
        for (int d = 1; d < 64; d <<= 1) s += __shfl_xor(s, d);
        if (lane == 0) atomicAdd(&JB[(j*3 + c)*11 + m], s);
    } else if (blk < 792 + 18144) {        // Bmat, K-tiled layout [k/32][vc][32]
        int gid = (blk - 792)*256 + tid;   // covers VCP*KP
        int vc = gid / KP, k = gid - vc*KP;
        float val;
        if (vc >= VC)     val = 0.f;
        else if (k < NB)  val = sdirs[vc*NB + k];
        else if (k < KC)  val = pdirs[vc*NP + (k - NB)];
        else if (k == KC) val = vtmpl[vc];
        else              val = 0.f;
        Bmat[((size_t)(k >> 5)*VCP + vc)*32 + (k & 31)] = f2bf(val);
    } else {                               // JbigT[vc/32][kc][vc%32] bf16: delta(kc%3,vc%3)*jreg[vc/3][kc/3]
        int gid = (blk - 792 - 18144)*256 + tid;   // covers 64*VCP
        int kc = gid / VCP, vc = gid - kc*VCP;
        float val = 0.f;
        if (kc < NK*3 && vc < VC && (kc % 3) == (vc % 3))
            val = jreg[(vc/3)*NK + (kc/3)];
        JbigT[((size_t)(vc >> 5)*64 + kc)*32 + (vc & 31)] = f2bf(val);
    }
}

// ---------------- K_pern: one WAVE per n (64-thread block; barriers ~free) ----------------
__global__ __launch_bounds__(64) void k_pern(const float* __restrict__ beta,
                                             const float* __restrict__ theta,
                                             const float* __restrict__ trans,
                                             const float* __restrict__ JB,
                                             unsigned short* __restrict__ Arow,
                                             unsigned short* __restrict__ Gt) {
    int n = blockIdx.x, tid = threadIdx.x;
    __shared__ float Rsm[NJ][9];
    __shared__ float Jsm[NJ][3];
    __shared__ float Gsm[NJ][12];   // 3x4, e = a*4+b

    if (tid < NJ) {                 // lanes 0-23: rodrigues
        const float* th = theta + (n*NJ + tid)*3;
        float x = th[0], y = th[1], z = th[2];
        float nrm = sqrtf(x*x + y*y + z*z);
        float t = fmaxf(nrm, 1.1754944e-38f);
        float inv = 1.0f / t;
        float rx = x*inv, ry = y*inv, rz = z*inv;
        float c = cosf(t), s = sinf(t), oc = 1.0f - c;
        Rsm[tid][0] = c + oc*rx*rx;      Rsm[tid][1] = oc*rx*ry - s*rz;  Rsm[tid][2] = oc*rx*rz + s*ry;
        Rsm[tid][3] = oc*ry*rx + s*rz;   Rsm[tid][4] = c + oc*ry*ry;     Rsm[tid][5] = oc*ry*rz - s*rx;
        Rsm[tid][6] = oc*rz*rx - s*ry;   Rsm[tid][7] = oc*rz*ry + s*rx;  Rsm[tid][8] = c + oc*rz*rz;
    } else if (tid < 2*NJ) {        // lanes 24-47: J rows (3 dots of 11 each)
        int j = tid - NJ;
        #pragma unroll
        for (int c = 0; c < 3; ++c) {
            float s = JB[(j*3+c)*11 + 0];
            #pragma unroll
            for (int b = 0; b < NB; ++b) s += JB[(j*3+c)*11 + 1 + b] * beta[n*NB + b];
            Jsm[j][c] = s;
        }
    }
    __syncthreads();

    if (tid < 12) {
        int a = tid >> 2, b = tid & 3;
        Gsm[0][a*4+b] = (b < 3) ? Rsm[0][a*3+b] : Jsm[0][a];
    }
    __syncthreads();
    for (int i = 1; i < NJ; ++i) {
        if (tid < 12) {
            int a = tid >> 2, b = tid & 3;
            int p = PAR[i];
            float acc = (b == 3) ? Gsm[p][a*4+3] : 0.0f;
            #pragma unroll
            for (int k = 0; k < 3; ++k) {
                float aval = (b < 3) ? Rsm[i][k*3+b] : (Jsm[i][k] - Jsm[p][k]);
                acc += Gsm[p][a*4+k] * aval;
            }
            Gsm[i][a*4+b] = acc;
        }
        __syncthreads();
    }
    if (tid < NJ) {   // t' = t - R.J + trans (trans folds: sum_j w = 1)
        int j = tid;
        #pragma unroll
        for (int a = 0; a < 3; ++a) {
            float t3 = Gsm[j][a*4+3]
                     - (Gsm[j][a*4+0]*Jsm[j][0] + Gsm[j][a*4+1]*Jsm[j][1] + Gsm[j][a*4+2]*Jsm[j][2])
                     + trans[n*3 + a];
            Gsm[j][a*4+3] = t3;
        }
    }
    __syncthreads();
    // Gt[n][e=0..15][j=0..31] bf16 zero-padded
    unsigned short* gt = Gt + n*512;
    for (int idx = tid; idx < 512; idx += 64) {
        int e = idx >> 5, j = idx & 31;
        float val = (e < 12 && j < NJ) ? Gsm[j][e] : 0.0f;
        gt[idx] = f2bf(val);
    }
    // A-row, K-tiled layout [k/32][n][32]
    for (int k = tid; k < KP; k += 64) {
        float val;
        if (k < NB) val = beta[n*NB + k];
        else if (k < KC) {
            int p = k - NB; int jj = p/9 + 1; int rr = p%9;
            val = Rsm[jj][rr] - ((rr==0 || rr==4 || rr==8) ? 1.0f : 0.0f);
        } else if (k == KC) val = 1.0f;
        else val = 0.0f;
        Arow[((size_t)(k >> 5)*NBATCH + n)*32 + (k & 31)] = f2bf(val);
    }
}

#define PIN2(a,b)             asm volatile("" :: "v"(a), "v"(b))
#define PIN3(a,b,c)           asm volatile("" :: "v"(a), "v"(b), "v"(c))
#define PIN4(a,b,c,d)         asm volatile("" :: "v"(a), "v"(b), "v"(c), "v"(d))

// ---------------- K_main: persistent n-loop; batch-issued loads; 1 barrier/iter; MFMA x2 ----------------
__global__ __launch_bounds__(256) void k_main(const unsigned short* __restrict__ Arow,
                                              const unsigned short* __restrict__ Bmat,
                                              const unsigned short* __restrict__ Gt,
                                              const float* __restrict__ weights,
                                              float* __restrict__ verts) {
    __shared__ __attribute__((aligned(16))) unsigned short vhsm[2][BN*VST4];   // 33280 B

    int tid = threadIdx.x;
    int wv = tid >> 6, lane = tid & 63;
    int l15 = lane & 15, jg = lane >> 4;
    int ns = blockIdx.x, vb = blockIdx.y;
    int v0 = vb * BV, vc0 = v0 * 3;
    int vcw0 = vc0 + wv*48;             // this wave's 48 vc columns

    // ---- B fragments hoisted once (21 loads, batch-issued) ----
    bh8 bfr[7][3];
    #pragma unroll
    for (int ks = 0; ks < 7; ++ks)
        #pragma unroll
        for (int ct = 0; ct < 3; ++ct)
            bfr[ks][ct] = *(const bh8*)(Bmat + ((size_t)ks*VCP + vcw0 + ct*16 + l15)*32 + jg*8);
    #pragma unroll
    for (int ks = 0; ks < 7; ++ks)
        PIN3(bfr[ks][0], bfr[ks][1], bfr[ks][2]);

    // ---- W fragments (B-operand of GEMM2) ----
    bh8 wfrag[4];
    #pragma unroll
    for (int mt = 0; mt < 4; ++mt) {
        int vr = v0 + mt*16 + l15;
        bh8 f = {0,0,0,0,0,0,0,0};
        if (jg < 3 && vr < V) {
            const float4* wp = (const float4*)(weights + (size_t)vr*NJ + jg*8);
            float4 w0 = wp[0], w1 = wp[1];
            f[0]=(short)f2bf(w0.x); f[1]=(short)f2bf(w0.y); f[2]=(short)f2bf(w0.z); f[3]=(short)f2bf(w0.w);
            f[4]=(short)f2bf(w1.x); f[5]=(short)f2bf(w1.y); f[6]=(short)f2bf(w1.z); f[7]=(short)f2bf(w1.w);
        }
        wfrag[mt] = f;
    }
    PIN4(wfrag[0], wfrag[1], wfrag[2], wfrag[3]);

    // per-lane spill column mapping (vc -> padded-4 col), constant across iters
    int c4[3];
    #pragma unroll
    for (int ct = 0; ct < 3; ++ct) {
        int vcw = wv*48 + ct*16 + l15;          // [0,192)
        c4[ct] = (vcw/3)*4 + vcw%3;
    }
    int tri = (((lane % 3)*16) + lane/3) * 4;   // bpermute byte index for output transpose

    // ---- prologue: A fragments for iter 0 (14 loads, batch-issued) ----
    bh8 af[7][2];
    {
        int n0 = ns*ITERS*BN;
        #pragma unroll
        for (int ks = 0; ks < 7; ++ks)
            #pragma unroll
            for (int mt = 0; mt < 2; ++mt)
                af[ks][mt] = *(const bh8*)(Arow + ((size_t)ks*NBATCH + n0 + mt*16 + l15)*32 + jg*8);
        #pragma unroll
        for (int ks = 0; ks < 7; ++ks)
            PIN2(af[ks][0], af[ks][1]);
    }

    int cur = 0;
    #pragma unroll 1
    for (int it = 0; it < ITERS; ++it) {
        int n0 = (ns*ITERS + it) * BN;

        // ---- G batch for this iter (8 loads in flight; consumed after the barrier) ----
        bh8 gfr[8];
        const unsigned short* gbase = Gt + ((size_t)(n0 + wv*8))*512 + l15*32 + jg*8;
        #pragma unroll
        for (int nl = 0; nl < 8; ++nl)
            gfr[nl] = *(const bh8*)(gbase + nl*512);
        PIN4(gfr[0], gfr[1], gfr[2], gfr[3]);
        PIN4(gfr[4], gfr[5], gfr[6], gfr[7]);

        // ---- GEMM1: vh = Arow . Bmat^T (all operands in registers) ----
        f32x4 acc[2][3] = {};
        #pragma unroll
        for (int ks = 0; ks < 7; ++ks)
            #pragma unroll
            for (int mt = 0; mt < 2; ++mt)
                #pragma unroll
                for (int ct = 0; ct < 3; ++ct)
                    acc[mt][ct] = __builtin_amdgcn_mfma_f32_16x16x32_bf16(af[ks][mt], bfr[ks][ct], acc[mt][ct], 0, 0, 0);

        // spill (bf16, padded-4): row = n_local, col = v*4+b  -> double buffer
        unsigned short* vs = &vhsm[cur][0];
        #pragma unroll
        for (int mt = 0; mt < 2; ++mt)
            #pragma unroll
            for (int ct = 0; ct < 3; ++ct)
                #pragma unroll
                for (int r = 0; r < 4; ++r)
                    vs[(mt*16 + jg*4 + r)*VST4 + c4[ct]] = f2bf(acc[mt][ct][r]);
        __syncthreads();   // single barrier per iter (dbuf makes WAR safe)

        // ---- A batch for next iter (hidden under GEMM2) ----
        if (it + 1 < ITERS) {
            int n1 = n0 + BN;
            #pragma unroll
            for (int ks = 0; ks < 7; ++ks)
                #pragma unroll
                for (int mt = 0; mt < 2; ++mt)
                    af[ks][mt] = *(const bh8*)(Arow + ((size_t)ks*NBATCH + n1 + mt*16 + l15)*32 + jg*8);
            #pragma unroll
            for (int ks = 0; ks < 7; ++ks)
                PIN2(af[ks][0], af[ks][1]);
        }

        // ---- GEMM2 + apply + transpose + plain store (L2 write-combined) ----
        #pragma unroll
        for (int nl = 0; nl < 8; ++nl) {
            int n_loc = wv*8 + nl;
            #pragma unroll
            for (int mt = 0; mt < 4; ++mt) {
                f32x4 z = {0.f, 0.f, 0.f, 0.f};
                f32x4 t = __builtin_amdgcn_mfma_f32_16x16x32_bf16(gfr[nl], wfrag[mt], z, 0, 0, 0);
                u16x4 vh4 = *(const u16x4*)&vs[n_loc*VST4 + (mt*16 + l15)*4];
                float p = t[0]*bf2f(vh4[0]) + t[1]*bf2f(vh4[1]) + t[2]*bf2f(vh4[2]) + t[3];
                float pp = __int_as_float(__builtin_amdgcn_ds_bpermute(tri, __float_as_int(p)));
                int col = vc0 + mt*48 + lane;
                if (lane < 48 && col < VC)
                    verts[(size_t)(n0 + n_loc)*VC + col] = pp;
            }
        }
        cur ^= 1;
    }
}

// ---------------- K_joints: LDS-staged MFMA GEMM  jpart[ks][n][kc] += verts x JbigT ----------------
__global__ __launch_bounds__(256) void k_joints(const float* __restrict__ verts,
                                                const unsigned short* __restrict__ JbigT,
                                                float* __restrict__ jpart) {
    __shared__ __attribute__((aligned(16))) unsigned short vt[32*128];   // 8 KB

    int tid = threadIdx.x;
    int lane = tid & 63, wv = tid >> 6;
    int l15 = lane & 15, jg = lane >> 4;
    int nt = blockIdx.x, ks = blockIdx.y;
    int n0 = nt * 32;
    int step0 = ks * (JCH*4);          // 36 k-steps per slice

    int row[4], c4[4];
    #pragma unroll
    for (int i = 0; i < 4; ++i) {
        int idx = i*256 + tid;         // 1024 16B-units = 32 rows x 32
        row[i] = idx >> 5; c4[i] = idx & 31;
    }

    float2 rg[8];
    auto issue = [&](int ch) {         // coalesced: consecutive lanes -> consecutive 8B
        int k0f = (step0 + ch*4) * 32;
        #pragma unroll
        for (int i = 0; i < 4; ++i) {
            const float* p = verts + (size_t)(n0 + row[i])*VC + k0f + c4[i]*4;
            rg[2*i+0] = *(const float2*)(p);
            rg[2*i+1] = *(const float2*)(p+2);
        }
    };

    issue(0);
    f32x4 acc[2] = {};
    #pragma unroll 1
    for (int ch = 0; ch < JCH; ++ch) {
        __syncthreads();               // prev chunk's fragment reads done
        #pragma unroll
        for (int i = 0; i < 4; ++i) {
            u16x4 w;
            w[0] = f2bf(rg[2*i].x); w[1] = f2bf(rg[2*i].y);
            w[2] = f2bf(rg[2*i+1].x); w[3] = f2bf(rg[2*i+1].y);
            int sidx = (row[i]*128 + c4[i]*4) ^ ((row[i] & 7) << 3);
            *(u16x4*)&vt[sidx] = w;
        }
        __syncthreads();
        if (ch + 1 < JCH) issue(ch + 1);   // overlap next-stage loads with MFMAs
        #pragma unroll
        for (int kk = 0; kk < 4; ++kk) {
            int r0 = l15, r1 = 16 + l15;
            bh8 a0 = *(const bh8*)&vt[(r0*128 + kk*32 + jg*8) ^ ((r0 & 7) << 3)];
            bh8 a1 = *(const bh8*)&vt[(r1*128 + kk*32 + jg*8) ^ ((r1 & 7) << 3)];
            bh8 b  = *(const bh8*)(JbigT + ((size_t)(step0 + ch*4 + kk)*64 + wv*16 + l15)*32 + jg*8);
            acc[0] = __builtin_amdgcn_mfma_f32_16x16x32_bf16(a0, b, acc[0], 0, 0, 0);
            acc[1] = __builtin_amdgcn_mfma_f32_16x16x32_bf16(a1, b, acc[1], 0, 0, 0);
        }
    }
    // D: col=lane&15 (kc within wave), row=(lane>>4)*4+r (n within 16-tile)
    float* jp = jpart + ((size_t)ks*NBATCH + n0)*64 + wv*16 + l15;
    #pragma unroll
    for (int mt = 0; mt < 2; ++mt)
        #pragma unroll
        for (int r = 0; r < 4; ++r)
            jp[(size_t)(mt*16 + jg*4 + r)*64] = acc[mt][r];
}

// ---------------- K_jred: joints[n, i] = sum_ks jpart[ks][n][i] ----------------
__global__ __launch_bounds__(256) void k_jred(const float* __restrict__ jpart,
                                              float* __restrict__ joints) {
    int idx = blockIdx.x*256 + threadIdx.x;
    if (idx >= NBATCH*NK*3) return;
    int n = idx / (NK*3), i = idx - n*(NK*3);
    float s = 0.f;
    #pragma unroll
    for (int ks = 0; ks < JSP; ++ks)
        s += jpart[((size_t)ks*NBATCH + n)*64 + i];
    joints[idx] = s;
}

extern "C" void kernel_launch(void* const* d_in, const int* in_sizes, int n_in,
                              void* d_out, int out_size, void* d_ws, size_t ws_size,
                              hipStream_t stream) {
    const float* beta  = (const float*)d_in[0];
    const float* theta = (const float*)d_in[1];
    const float* trans = (const float*)d_in[2];
    const float* sdirs = (const float*)d_in[3];
    const float* vtmpl = (const float*)d_in[4];
    const float* jregJ = (const float*)d_in[5];
    const float* pdirs = (const float*)d_in[6];
    const float* wgts  = (const float*)d_in[7];
    const float* jregK = (const float*)d_in[8];

    float* verts  = (float*)d_out;
    float* joints = verts + (size_t)NBATCH * VC;

    char* ws = (char*)d_ws;
    float*          JB    = (float*)ws;                                      // 4096 B (zeroed)
    unsigned short* Arow  = (unsigned short*)(ws + 4096);                    // 917504 B
    unsigned short* Gt    = (unsigned short*)(ws + 4096 + 917504);           // 2097152 B
    unsigned short* Bmat  = (unsigned short*)(ws + 4096 + 917504 + 2097152); // 9289728 B
    unsigned short* JbigT = (unsigned short*)(ws + 4096 + 917504 + 2097152 + 9289728); // 648*64*32*2 = 2654208
    float*          jpart = (float*)(ws + 4096 + 917504 + 2097152 + 9289728 + 2654208); // 18*2048*64*4 = 9437184

    hipMemsetAsync(JB, 0, 4096, stream);

    k_prep <<<792 + 18144 + 5184, 256, 0, stream>>>(jregJ, vtmpl, sdirs, pdirs, jregK, JB, Bmat, JbigT);
    k_pern <<<NBATCH, 64, 0, stream>>>(beta, theta, trans, JB, Arow, Gt);
    dim3 g4(NSPLIT, (V + BV - 1)/BV);   // (16, 108)
    k_main <<<g4, 256, 0, stream>>>(Arow, Bmat, Gt, wgts, verts);
    dim3 g5(NBATCH/BN, JSP);            // (64, 18)
    k_joints<<<g5, 256, 0, stream>>>(verts, JbigT, jpart);
    k_jred <<<(NBATCH*NK*3 + 255)/256, 256, 0, stream>>>(jpart, joints);
}

// Round 9
// 174.918 us; speedup vs baseline: 1.8082x; 1.0147x over previous
//
#include <hip/hip_runtime.h>

#define V      6890
#define NJ     24
#define NB     10
#define NP     207
#define NK     19
#define NBATCH 2048
#define KP     224      // padded K: 10 beta + 207 lrotmin + 1 const + 6 zero
#define KC     217      // constant-1 column (-> v_template)
#define VC     (V*3)    // 20670
#define VCP    20736    // padded VC (= 108*64*3)
#define BN     32       // n-tile
#define BV     64       // v-tile per block
#define NSPLIT 16
#define ITERS  (NBATCH/BN/NSPLIT)   // 4 n-tiles per block
#define VST4   260      // vhsm row stride in shorts (520 B: 8B-aligned, jg-groups 8 banks apart)
#define VSEG   1723     // ceil(V/4) for V-splits (k_prep JB dots)
#define KSTEPS 648      // VCP/32
#define JSP    18       // joints GEMM K-split (18 slices x 9 chunks x 4 steps = 648)
#define JCH    9        // chunks per slice; chunk = 4 k-steps = 128 floats

using bh8   = __attribute__((ext_vector_type(8))) short;          // 8 x bf16
using u16x4 = __attribute__((ext_vector_type(4))) unsigned short;
using f32x4 = __attribute__((ext_vector_type(4))) float;

__constant__ int PAR[NJ] = {-1,0,0,0,1,2,3,4,5,6,7,8,9,9,9,12,13,14,16,17,18,19,20,21};

__device__ __forceinline__ unsigned short f2bf(float f) {
    unsigned int u = __float_as_uint(f);
    u += 0x7FFFu + ((u >> 16) & 1u);   // RNE; no NaNs in this data
    return (unsigned short)(u >> 16);
}
__device__ __forceinline__ float bf2f(unsigned short h) {
    return __uint_as_float((unsigned int)h << 16);
}

// ---------------- K_prep: fused [k_jb(V-split, atomic) | k_bmat(K-tiled) | JbigT(K-tiled)] ----------------
__global__ __launch_bounds__(256) void k_prep(const float* __restrict__ Jreg,
                                              const float* __restrict__ vtmpl,
                                              const float* __restrict__ sdirs,
                                              const float* __restrict__ pdirs,
                                              const float* __restrict__ jreg,
                                              float* __restrict__ JB,
                                              unsigned short* __restrict__ Bmat,
                                              unsigned short* __restrict__ JbigT) {
    int blk = blockIdx.x, tid = threadIdx.x;
    if (blk < 792) {                       // JB partial dots, 4-way V-split, atomic accumulate
        int vs = blk & 3, og = blk >> 2;
        int o = og*4 + (tid >> 6);         // o in [0,792) = 24*33
        int lane = tid & 63;
        int j = o/33, t = o%33, c = t/11, m = t%11;
        int lo = vs*VSEG + lane, hi = min(V, vs*VSEG + VSEG);
        const float* jr = Jreg + j*V;
        float s = 0.f;
        if (m == 0) { for (int v = lo; v < hi; v += 64) s += jr[v] * vtmpl[v*3 + c]; }
        else        { for (int v = lo; v < hi; v += 64) s += jr[v] * sdirs[(v*3 + c)*NB + (m-1)]; }
        #pragma unroll
        for (int d = 1; d < 64; d <<= 1) s += __shfl_xor(s, d);
        if (lane == 0) atomicAdd(&JB[(j*3 + c)*11 + m], s);
    } else if (blk < 792 + 18144) {        // Bmat, K-tiled layout [k/32][vc][32]
        int gid = (blk - 792)*256 + tid;   // covers VCP*KP
        int vc = gid / KP, k = gid - vc*KP;
        float val;
        if (vc >= VC)     val = 0.f;
        else if (k < NB)  val = sdirs[vc*NB + k];
        else if (k < KC)  val = pdirs[vc*NP + (k - NB)];
        else if (k == KC) val = vtmpl[vc];
        else              val = 0.f;
        Bmat[((size_t)(k >> 5)*VCP + vc)*32 + (k & 31)] = f2bf(val);
    } else {                               // JbigT[vc/32][kc][vc%32] bf16: delta(kc%3,vc%3)*jreg[vc/3][kc/3]
        int gid = (blk - 792 - 18144)*256 + tid;   // covers 64*VCP
        int kc = gid / VCP, vc = gid - kc*VCP;
        float val = 0.f;
        if (kc < NK*3 && vc < VC && (kc % 3) == (vc % 3))
            val = jreg[(vc/3)*NK + (kc/3)];
        JbigT[((size_t)(vc >> 5)*64 + kc)*32 + (vc & 31)] = f2bf(val);
    }
}

// ---------------- K_pern: one WAVE per n (64-thread block; barriers ~free) ----------------
__global__ __launch_bounds__(64) void k_pern(const float* __restrict__ beta,
                                             const float* __restrict__ theta,
                                             const float* __restrict__ trans,
                                             const float* __restrict__ JB,
                                             unsigned short* __restrict__ Arow,
                                             unsigned short* __restrict__ Gt) {
    int n = blockIdx.x, tid = threadIdx.x;
    __shared__ float Rsm[NJ][9];
    __shared__ float Jsm[NJ][3];
    __shared__ float Gsm[NJ][12];   // 3x4, e = a*4+b

    if (tid < NJ) {                 // lanes 0-23: rodrigues
        const float* th = theta + (n*NJ + tid)*3;
        float x = th[0], y = th[1], z = th[2];
        float nrm = sqrtf(x*x + y*y + z*z);
        float t = fmaxf(nrm, 1.1754944e-38f);
        float inv = 1.0f / t;
        float rx = x*inv, ry = y*inv, rz = z*inv;
        float c = cosf(t), s = sinf(t), oc = 1.0f - c;
        Rsm[tid][0] = c + oc*rx*rx;      Rsm[tid][1] = oc*rx*ry - s*rz;  Rsm[tid][2] = oc*rx*rz + s*ry;
        Rsm[tid][3] = oc*ry*rx + s*rz;   Rsm[tid][4] = c + oc*ry*ry;     Rsm[tid][5] = oc*ry*rz - s*rx;
        Rsm[tid][6] = oc*rz*rx - s*ry;   Rsm[tid][7] = oc*rz*ry + s*rx;  Rsm[tid][8] = c + oc*rz*rz;
    } else if (tid < 2*NJ) {        // lanes 24-47: J rows (3 dots of 11 each)
        int j = tid - NJ;
        #pragma unroll
        for (int c = 0; c < 3; ++c) {
            float s = JB[(j*3+c)*11 + 0];
            #pragma unroll
            for (int b = 0; b < NB; ++b) s += JB[(j*3+c)*11 + 1 + b] * beta[n*NB + b];
            Jsm[j][c] = s;
        }
    }
    __syncthreads();

    if (tid < 12) {
        int a = tid >> 2, b = tid & 3;
        Gsm[0][a*4+b] = (b < 3) ? Rsm[0][a*3+b] : Jsm[0][a];
    }
    __syncthreads();
    for (int i = 1; i < NJ; ++i) {
        if (tid < 12) {
            int a = tid >> 2, b = tid & 3;
            int p = PAR[i];
            float acc = (b == 3) ? Gsm[p][a*4+3] : 0.0f;
            #pragma unroll
            for (int k = 0; k < 3; ++k) {
                float aval = (b < 3) ? Rsm[i][k*3+b] : (Jsm[i][k] - Jsm[p][k]);
                acc += Gsm[p][a*4+k] * aval;
            }
            Gsm[i][a*4+b] = acc;
        }
        __syncthreads();
    }
    if (tid < NJ) {   // t' = t - R.J + trans (trans folds: sum_j w = 1)
        int j = tid;
        #pragma unroll
        for (int a = 0; a < 3; ++a) {
            float t3 = Gsm[j][a*4+3]
                     - (Gsm[j][a*4+0]*Jsm[j][0] + Gsm[j][a*4+1]*Jsm[j][1] + Gsm[j][a*4+2]*Jsm[j][2])
                     + trans[n*3 + a];
            Gsm[j][a*4+3] = t3;
        }
    }
    __syncthreads();
    // Gt[n][e=0..15][j=0..31] bf16 zero-padded
    unsigned short* gt = Gt + n*512;
    for (int idx = tid; idx < 512; idx += 64) {
        int e = idx >> 5, j = idx & 31;
        float val = (e < 12 && j < NJ) ? Gsm[j][e] : 0.0f;
        gt[idx] = f2bf(val);
    }
    // A-row, K-tiled layout [k/32][n][32]
    for (int k = tid; k < KP; k += 64) {
        float val;
        if (k < NB) val = beta[n*NB + k];
        else if (k < KC) {
            int p = k - NB; int jj = p/9 + 1; int rr = p%9;
            val = Rsm[jj][rr] - ((rr==0 || rr==4 || rr==8) ? 1.0f : 0.0f);
        } else if (k == KC) val = 1.0f;
        else val = 0.0f;
        Arow[((size_t)(k >> 5)*NBATCH + n)*32 + (k & 31)] = f2bf(val);
    }
}

#define PIN2(a,b)             asm volatile("" :: "v"(a), "v"(b))
#define PIN3(a,b,c)           asm volatile("" :: "v"(a), "v"(b), "v"(c))
#define PIN4(a,b,c,d)         asm volatile("" :: "v"(a), "v"(b), "v"(c), "v"(d))

// ---------------- K_main: persistent n-loop; batch-issued loads; 1 barrier/iter; MFMA x2 ----------------
// launch_bounds(256, 2): VGPR cap 256 -> the ~227 live regs (bfr84+wfrag16+af56+gfr32+acc24+misc)
// FIT with no scratch spill (R8 at default cap=128 spilled ~100 regs -> scratch-bound).
__global__ __launch_bounds__(256, 2) void k_main(const unsigned short* __restrict__ Arow,
                                                 const unsigned short* __restrict__ Bmat,
                                                 const unsigned short* __restrict__ Gt,
                                                 const float* __restrict__ weights,
                                                 float* __restrict__ verts) {
    __shared__ __attribute__((aligned(16))) unsigned short vhsm[2][BN*VST4];   // 33280 B

    int tid = threadIdx.x;
    int wv = tid >> 6, lane = tid & 63;
    int l15 = lane & 15, jg = lane >> 4;
    int ns = blockIdx.x, vb = blockIdx.y;
    int v0 = vb * BV, vc0 = v0 * 3;
    int vcw0 = vc0 + wv*48;             // this wave's 48 vc columns

    // ---- B fragments hoisted once (21 loads, batch-issued) ----
    bh8 bfr[7][3];
    #pragma unroll
    for (int ks = 0; ks < 7; ++ks)
        #pragma unroll
        for (int ct = 0; ct < 3; ++ct)
            bfr[ks][ct] = *(const bh8*)(Bmat + ((size_t)ks*VCP + vcw0 + ct*16 + l15)*32 + jg*8);
    #pragma unroll
    for (int ks = 0; ks < 7; ++ks)
        PIN3(bfr[ks][0], bfr[ks][1], bfr[ks][2]);

    // ---- W fragments (B-operand of GEMM2) ----
    bh8 wfrag[4];
    #pragma unroll
    for (int mt = 0; mt < 4; ++mt) {
        int vr = v0 + mt*16 + l15;
        bh8 f = {0,0,0,0,0,0,0,0};
        if (jg < 3 && vr < V) {
            const float4* wp = (const float4*)(weights + (size_t)vr*NJ + jg*8);
            float4 w0 = wp[0], w1 = wp[1];
            f[0]=(short)f2bf(w0.x); f[1]=(short)f2bf(w0.y); f[2]=(short)f2bf(w0.z); f[3]=(short)f2bf(w0.w);
            f[4]=(short)f2bf(w1.x); f[5]=(short)f2bf(w1.y); f[6]=(short)f2bf(w1.z); f[7]=(short)f2bf(w1.w);
        }
        wfrag[mt] = f;
    }
    PIN4(wfrag[0], wfrag[1], wfrag[2], wfrag[3]);

    // per-lane spill column mapping (vc -> padded-4 col), constant across iters
    int c4[3];
    #pragma unroll
    for (int ct = 0; ct < 3; ++ct) {
        int vcw = wv*48 + ct*16 + l15;          // [0,192)
        c4[ct] = (vcw/3)*4 + vcw%3;
    }
    int tri = (((lane % 3)*16) + lane/3) * 4;   // bpermute byte index for output transpose

    // ---- prologue: A fragments for iter 0 (14 loads, batch-issued) ----
    bh8 af[7][2];
    {
        int n0 = ns*ITERS*BN;
        #pragma unroll
        for (int ks = 0; ks < 7; ++ks)
            #pragma unroll
            for (int mt = 0; mt < 2; ++mt)
                af[ks][mt] = *(const bh8*)(Arow + ((size_t)ks*NBATCH + n0 + mt*16 + l15)*32 + jg*8);
        #pragma unroll
        for (int ks = 0; ks < 7; ++ks)
            PIN2(af[ks][0], af[ks][1]);
    }

    int cur = 0;
    #pragma unroll 1
    for (int it = 0; it < ITERS; ++it) {
        int n0 = (ns*ITERS + it) * BN;

        // ---- G batch for this iter (8 loads in flight; consumed after the barrier) ----
        bh8 gfr[8];
        const unsigned short* gbase = Gt + ((size_t)(n0 + wv*8))*512 + l15*32 + jg*8;
        #pragma unroll
        for (int nl = 0; nl < 8; ++nl)
            gfr[nl] = *(const bh8*)(gbase + nl*512);
        PIN4(gfr[0], gfr[1], gfr[2], gfr[3]);
        PIN4(gfr[4], gfr[5], gfr[6], gfr[7]);

        // ---- GEMM1: vh = Arow . Bmat^T (all operands in registers) ----
        f32x4 acc[2][3] = {};
        #pragma unroll
        for (int ks = 0; ks < 7; ++ks)
            #pragma unroll
            for (int mt = 0; mt < 2; ++mt)
                #pragma unroll
                for (int ct = 0; ct < 3; ++ct)
                    acc[mt][ct] = __builtin_amdgcn_mfma_f32_16x16x32_bf16(af[ks][mt], bfr[ks][ct], acc[mt][ct], 0, 0, 0);

        // spill (bf16, padded-4): row = n_local, col = v*4+b  -> double buffer
        unsigned short* vs = &vhsm[cur][0];
        #pragma unroll
        for (int mt = 0; mt < 2; ++mt)
            #pragma unroll
            for (int ct = 0; ct < 3; ++ct)
                #pragma unroll
                for (int r = 0; r < 4; ++r)
                    vs[(mt*16 + jg*4 + r)*VST4 + c4[ct]] = f2bf(acc[mt][ct][r]);
        __syncthreads();   // single barrier per iter (dbuf makes WAR safe)

        // ---- A batch for next iter (hidden under GEMM2) ----
        if (it + 1 < ITERS) {
            int n1 = n0 + BN;
            #pragma unroll
            for (int ks = 0; ks < 7; ++ks)
                #pragma unroll
                for (int mt = 0; mt < 2; ++mt)
                    af[ks][mt] = *(const bh8*)(Arow + ((size_t)ks*NBATCH + n1 + mt*16 + l15)*32 + jg*8);
            #pragma unroll
            for (int ks = 0; ks < 7; ++ks)
                PIN2(af[ks][0], af[ks][1]);
        }

        // ---- GEMM2 + apply + transpose + plain store (L2 write-combined) ----
        #pragma unroll
        for (int nl = 0; nl < 8; ++nl) {
            int n_loc = wv*8 + nl;
            #pragma unroll
            for (int mt = 0; mt < 4; ++mt) {
                f32x4 z = {0.f, 0.f, 0.f, 0.f};
                f32x4 t = __builtin_amdgcn_mfma_f32_16x16x32_bf16(gfr[nl], wfrag[mt], z, 0, 0, 0);
                u16x4 vh4 = *(const u16x4*)&vs[n_loc*VST4 + (mt*16 + l15)*4];
                float p = t[0]*bf2f(vh4[0]) + t[1]*bf2f(vh4[1]) + t[2]*bf2f(vh4[2]) + t[3];
                float pp = __int_as_float(__builtin_amdgcn_ds_bpermute(tri, __float_as_int(p)));
                int col = vc0 + mt*48 + lane;
                if (lane < 48 && col < VC)
                    verts[(size_t)(n0 + n_loc)*VC + col] = pp;
            }
        }
        cur ^= 1;
    }
}

// ---------------- K_joints: LDS-staged MFMA GEMM  jpart[ks][n][kc] += verts x JbigT ----------------
__global__ __launch_bounds__(256) void k_joints(const float* __restrict__ verts,
                                                const unsigned short* __restrict__ JbigT,
                                                float* __restrict__ jpart) {
    __shared__ __attribute__((aligned(16))) unsigned short vt[32*128];   // 8 KB

    int tid = threadIdx.x;
    int lane = tid & 63, wv = tid >> 6;
    int l15 = lane & 15, jg = lane >> 4;
    int nt = blockIdx.x, ks = blockIdx.y;
    int n0 = nt * 32;
    int step0 = ks * (JCH*4);          // 36 k-steps per slice

    int row[4], c4[4];
    #pragma unroll
    for (int i = 0; i < 4; ++i) {
        int idx = i*256 + tid;         // 1024 16B-units = 32 rows x 32
        row[i] = idx >> 5; c4[i] = idx & 31;
    }

    float2 rg[8];
    auto issue = [&](int ch) {         // coalesced: consecutive lanes -> consecutive 8B
        int k0f = (step0 + ch*4) * 32;
        #pragma unroll
        for (int i = 0; i < 4; ++i) {
            const float* p = verts + (size_t)(n0 + row[i])*VC + k0f + c4[i]*4;
            rg[2*i+0] = *(const float2*)(p);
            rg[2*i+1] = *(const float2*)(p+2);
        }
    };

    issue(0);
    f32x4 acc[2] = {};
    #pragma unroll 1
    for (int ch = 0; ch < JCH; ++ch) {
        __syncthreads();               // prev chunk's fragment reads done
        #pragma unroll
        for (int i = 0; i < 4; ++i) {
            u16x4 w;
            w[0] = f2bf(rg[2*i].x); w[1] = f2bf(rg[2*i].y);
            w[2] = f2bf(rg[2*i+1].x); w[3] = f2bf(rg[2*i+1].y);
            int sidx = (row[i]*128 + c4[i]*4) ^ ((row[i] & 7) << 3);
            *(u16x4*)&vt[sidx] = w;
        }
        __syncthreads();
        if (ch + 1 < JCH) issue(ch + 1);   // overlap next-stage loads with MFMAs
        #pragma unroll
        for (int kk = 0; kk < 4; ++kk) {
            int r0 = l15, r1 = 16 + l15;
            bh8 a0 = *(const bh8*)&vt[(r0*128 + kk*32 + jg*8) ^ ((r0 & 7) << 3)];
            bh8 a1 = *(const bh8*)&vt[(r1*128 + kk*32 + jg*8) ^ ((r1 & 7) << 3)];
            bh8 b  = *(const bh8*)(JbigT + ((size_t)(step0 + ch*4 + kk)*64 + wv*16 + l15)*32 + jg*8);
            acc[0] = __builtin_amdgcn_mfma_f32_16x16x32_bf16(a0, b, acc[0], 0, 0, 0);
            acc[1] = __builtin_amdgcn_mfma_f32_16x16x32_bf16(a1, b, acc[1], 0, 0, 0);
        }
    }
    // D: col=lane&15 (kc within wave), row=(lane>>4)*4+r (n within 16-tile)
    float* jp = jpart + ((size_t)ks*NBATCH + n0)*64 + wv*16 + l15;
    #pragma unroll
    for (int mt = 0; mt < 2; ++mt)
        #pragma unroll
        for (int r = 0; r < 4; ++r)
            jp[(size_t)(mt*16 + jg*4 + r)*64] = acc[mt][r];
}

// ---------------- K_jred: joints[n, i] = sum_ks jpart[ks][n][i] ----------------
__global__ __launch_bounds__(256) void k_jred(const float* __restrict__ jpart,
                                              float* __restrict__ joints) {
    int idx = blockIdx.x*256 + threadIdx.x;
    if (idx >= NBATCH*NK*3) return;
    int n = idx / (NK*3), i = idx - n*(NK*3);
    float s = 0.f;
    #pragma unroll
    for (int ks = 0; ks < JSP; ++ks)
        s += jpart[((size_t)ks*NBATCH + n)*64 + i];
    joints[idx] = s;
}

extern "C" void kernel_launch(void* const* d_in, const int* in_sizes, int n_in,
                              void* d_out, int out_size, void* d_ws, size_t ws_size,
                              hipStream_t stream) {
    const float* beta  = (const float*)d_in[0];
    const float* theta = (const float*)d_in[1];
    const float* trans = (const float*)d_in[2];
    const float* sdirs = (const float*)d_in[3];
    const float* vtmpl = (const float*)d_in[4];
    const float* jregJ = (const float*)d_in[5];
    const float* pdirs = (const float*)d_in[6];
    const float* wgts  = (const float*)d_in[7];
    const float* jregK = (const float*)d_in[8];

    float* verts  = (float*)d_out;
    float* joints = verts + (size_t)NBATCH * VC;

    char* ws = (char*)d_ws;
    float*          JB    = (float*)ws;                                      // 4096 B (zeroed)
    unsigned short* Arow  = (unsigned short*)(ws + 4096);                    // 917504 B
    unsigned short* Gt    = (unsigned short*)(ws + 4096 + 917504);           // 2097152 B
    unsigned short* Bmat  = (unsigned short*)(ws + 4096 + 917504 + 2097152); // 9289728 B
    unsigned short* JbigT = (unsigned short*)(ws + 4096 + 917504 + 2097152 + 9289728); // 648*64*32*2 = 2654208
    float*          jpart = (float*)(ws + 4096 + 917504 + 2097152 + 9289728 + 2654208); // 18*2048*64*4 = 9437184

    hipMemsetAsync(JB, 0, 4096, stream);

    k_prep <<<792 + 18144 + 5184, 256, 0, stream>>>(jregJ, vtmpl, sdirs, pdirs, jregK, JB, Bmat, JbigT);
    k_pern <<<NBATCH, 64, 0, stream>>>(beta, theta, trans, JB, Arow, Gt);
    dim3 g4(NSPLIT, (V + BV - 1)/BV);   // (16, 108)
    k_main <<<g4, 256, 0, stream>>>(Arow, Bmat, Gt, wgts, verts);
    dim3 g5(NBATCH/BN, JSP);            // (64, 18)
    k_joints<<<g5, 256, 0, stream>>>(verts, JbigT, jpart);
    k_jred <<<(NBATCH*NK*3 + 255)/256, 256, 0, stream>>>(jpart, joints);
}

// Round 10
// 161.911 us; speedup vs baseline: 1.9535x; 1.0803x over previous
//
#include <hip/hip_runtime.h>

#define V      6890
#define NJ     24
#define NB     10
#define NP     207
#define NK     19
#define NBATCH 2048
#define KP     224      // padded K: 10 beta + 207 lrotmin + 1 const + 6 zero
#define KC     217      // constant-1 column (-> v_template)
#define VC     (V*3)    // 20670
#define VCP    20736    // padded VC (= 108*64*3)
#define BN     32       // n-tile
#define BV     64       // v-tile per block
#define VST4   260      // vhsm row stride in shorts (520 B: 8B-aligned, jg-groups 8 banks apart)
#define VSEG   1723     // ceil(V/4) for V-splits (k_prep JB dots)
#define KSTEPS 648      // VCP/32
#define JSP    18       // joints GEMM K-split (18 slices x 9 chunks x 4 steps = 648)
#define JCH    9        // chunks per slice; chunk = 4 k-steps = 128 floats

using bh8   = __attribute__((ext_vector_type(8))) short;          // 8 x bf16
using u16x4 = __attribute__((ext_vector_type(4))) unsigned short;
using f32x4 = __attribute__((ext_vector_type(4))) float;

__constant__ int PAR[NJ] = {-1,0,0,0,1,2,3,4,5,6,7,8,9,9,9,12,13,14,16,17,18,19,20,21};

__device__ __forceinline__ unsigned short f2bf(float f) {
    unsigned int u = __float_as_uint(f);
    u += 0x7FFFu + ((u >> 16) & 1u);   // RNE; no NaNs in this data
    return (unsigned short)(u >> 16);
}
__device__ __forceinline__ float bf2f(unsigned short h) {
    return __uint_as_float((unsigned int)h << 16);
}

// ---------------- K_prep: fused [k_jb(V-split, atomic) | k_bmat(K-tiled) | JbigT(K-tiled)] ----------------
__global__ __launch_bounds__(256) void k_prep(const float* __restrict__ Jreg,
                                              const float* __restrict__ vtmpl,
                                              const float* __restrict__ sdirs,
                                              const float* __restrict__ pdirs,
                                              const float* __restrict__ jreg,
                                              float* __restrict__ JB,
                                              unsigned short* __restrict__ Bmat,
                                              unsigned short* __restrict__ JbigT) {
    int blk = blockIdx.x, tid = threadIdx.x;
    if (blk < 792) {                       // JB partial dots, 4-way V-split, atomic accumulate
        int vs = blk & 3, og = blk >> 2;
        int o = og*4 + (tid >> 6);         // o in [0,792) = 24*33
        int lane = tid & 63;
        int j = o/33, t = o%33, c = t/11, m = t%11;
        int lo = vs*VSEG + lane, hi = min(V, vs*VSEG + VSEG);
        const float* jr = Jreg + j*V;
        float s = 0.f;
        if (m == 0) { for (int v = lo; v < hi; v += 64) s += jr[v] * vtmpl[v*3 + c]; }
        else        { for (int v = lo; v < hi; v += 64) s += jr[v] * sdirs[(v*3 + c)*NB + (m-1)]; }
        #pragma unroll
        for (int d = 1; d < 64; d <<= 1) s += __shfl_xor(s, d);
        if (lane == 0) atomicAdd(&JB[(j*3 + c)*11 + m], s);
    } else if (blk < 792 + 18144) {        // Bmat, K-tiled layout [k/32][vc][32]
        int gid = (blk - 792)*256 + tid;   // covers VCP*KP
        int vc = gid / KP, k = gid - vc*KP;
        float val;
        if (vc >= VC)     val = 0.f;
        else if (k < NB)  val = sdirs[vc*NB + k];
        else if (k < KC)  val = pdirs[vc*NP + (k - NB)];
        else if (k == KC) val = vtmpl[vc];
        else              val = 0.f;
        Bmat[((size_t)(k >> 5)*VCP + vc)*32 + (k & 31)] = f2bf(val);
    } else {                               // JbigT[vc/32][kc][vc%32] bf16: delta(kc%3,vc%3)*jreg[vc/3][kc/3]
        int gid = (blk - 792 - 18144)*256 + tid;   // covers 64*VCP
        int kc = gid / VCP, vc = gid - kc*VCP;
        float val = 0.f;
        if (kc < NK*3 && vc < VC && (kc % 3) == (vc % 3))
            val = jreg[(vc/3)*NK + (kc/3)];
        JbigT[((size_t)(vc >> 5)*64 + kc)*32 + (vc & 31)] = f2bf(val);
    }
}

// ---------------- K_pern: one WAVE per n (64-thread block; barriers ~free) ----------------
__global__ __launch_bounds__(64) void k_pern(const float* __restrict__ beta,
                                             const float* __restrict__ theta,
                                             const float* __restrict__ trans,
                                             const float* __restrict__ JB,
                                             unsigned short* __restrict__ Arow,
                                             unsigned short* __restrict__ Gt) {
    int n = blockIdx.x, tid = threadIdx.x;
    __shared__ float Rsm[NJ][9];
    __shared__ float Jsm[NJ][3];
    __shared__ float Gsm[NJ][12];   // 3x4, e = a*4+b

    if (tid < NJ) {                 // lanes 0-23: rodrigues
        const float* th = theta + (n*NJ + tid)*3;
        float x = th[0], y = th[1], z = th[2];
        float nrm = sqrtf(x*x + y*y + z*z);
        float t = fmaxf(nrm, 1.1754944e-38f);
        float inv = 1.0f / t;
        float rx = x*inv, ry = y*inv, rz = z*inv;
        float c = cosf(t), s = sinf(t), oc = 1.0f - c;
        Rsm[tid][0] = c + oc*rx*rx;      Rsm[tid][1] = oc*rx*ry - s*rz;  Rsm[tid][2] = oc*rx*rz + s*ry;
        Rsm[tid][3] = oc*ry*rx + s*rz;   Rsm[tid][4] = c + oc*ry*ry;     Rsm[tid][5] = oc*ry*rz - s*rx;
        Rsm[tid][6] = oc*rz*rx - s*ry;   Rsm[tid][7] = oc*rz*ry + s*rx;  Rsm[tid][8] = c + oc*rz*rz;
    } else if (tid < 2*NJ) {        // lanes 24-47: J rows (3 dots of 11 each)
        int j = tid - NJ;
        #pragma unroll
        for (int c = 0; c < 3; ++c) {
            float s = JB[(j*3+c)*11 + 0];
            #pragma unroll
            for (int b = 0; b < NB; ++b) s += JB[(j*3+c)*11 + 1 + b] * beta[n*NB + b];
            Jsm[j][c] = s;
        }
    }
    __syncthreads();

    if (tid < 12) {
        int a = tid >> 2, b = tid & 3;
        Gsm[0][a*4+b] = (b < 3) ? Rsm[0][a*3+b] : Jsm[0][a];
    }
    __syncthreads();
    for (int i = 1; i < NJ; ++i) {
        if (tid < 12) {
            int a = tid >> 2, b = tid & 3;
            int p = PAR[i];
            float acc = (b == 3) ? Gsm[p][a*4+3] : 0.0f;
            #pragma unroll
            for (int k = 0; k < 3; ++k) {
                float aval = (b < 3) ? Rsm[i][k*3+b] : (Jsm[i][k] - Jsm[p][k]);
                acc += Gsm[p][a*4+k] * aval;
            }
            Gsm[i][a*4+b] = acc;
        }
        __syncthreads();
    }
    if (tid < NJ) {   // t' = t - R.J + trans (trans folds: sum_j w = 1)
        int j = tid;
        #pragma unroll
        for (int a = 0; a < 3; ++a) {
            float t3 = Gsm[j][a*4+3]
                     - (Gsm[j][a*4+0]*Jsm[j][0] + Gsm[j][a*4+1]*Jsm[j][1] + Gsm[j][a*4+2]*Jsm[j][2])
                     + trans[n*3 + a];
            Gsm[j][a*4+3] = t3;
        }
    }
    __syncthreads();
    // Gt[n][e=0..15][j=0..31] bf16 zero-padded
    unsigned short* gt = Gt + n*512;
    for (int idx = tid; idx < 512; idx += 64) {
        int e = idx >> 5, j = idx & 31;
        float val = (e < 12 && j < NJ) ? Gsm[j][e] : 0.0f;
        gt[idx] = f2bf(val);
    }
    // A-row, K-tiled layout [k/32][n][32]
    for (int k = tid; k < KP; k += 64) {
        float val;
        if (k < NB) val = beta[n*NB + k];
        else if (k < KC) {
            int p = k - NB; int jj = p/9 + 1; int rr = p%9;
            val = Rsm[jj][rr] - ((rr==0 || rr==4 || rr==8) ? 1.0f : 0.0f);
        } else if (k == KC) val = 1.0f;
        else val = 0.0f;
        Arow[((size_t)(k >> 5)*NBATCH + n)*32 + (k & 31)] = f2bf(val);
    }
}

// ---------------- K_main: streaming loads, max TLP; one (n-tile, v-tile) per block ----------------
// R10: stop fighting the register allocator (R7-R9 hoists all failed: compiler
// capped at 124-128 VGPR and serialized). Instead: stream fragments per ks from
// the dense K-tiled layouts (1 instr = 1KB contiguous), keep VGPR ~<=128, grid
// 6912 blocks -> 4-6 waves/SIMD of TLP to cover L2 latency.
__global__ __launch_bounds__(256, 4) void k_main(const unsigned short* __restrict__ Arow,
                                                 const unsigned short* __restrict__ Bmat,
                                                 const unsigned short* __restrict__ Gt,
                                                 const float* __restrict__ weights,
                                                 float* __restrict__ verts) {
    __shared__ __attribute__((aligned(16))) unsigned short vhsm[BN*VST4];   // 16640 B

    int tid = threadIdx.x;
    int wv = tid >> 6, lane = tid & 63;
    int l15 = lane & 15, jg = lane >> 4;
    int nb = blockIdx.x, vb = blockIdx.y;      // x-fastest: 64 consecutive blocks share B slice
    int n0 = nb * BN, v0 = vb * BV, vc0 = v0 * 3;
    int vcw0 = vc0 + wv*48;

    // W fragments (B-operand of GEMM2), 16 VGPR, loaded once
    bh8 wfrag[4];
    #pragma unroll
    for (int mt = 0; mt < 4; ++mt) {
        int vr = v0 + mt*16 + l15;
        bh8 f = {0,0,0,0,0,0,0,0};
        if (jg < 3 && vr < V) {
            const float4* wp = (const float4*)(weights + (size_t)vr*NJ + jg*8);
            float4 w0 = wp[0], w1 = wp[1];
            f[0]=(short)f2bf(w0.x); f[1]=(short)f2bf(w0.y); f[2]=(short)f2bf(w0.z); f[3]=(short)f2bf(w0.w);
            f[4]=(short)f2bf(w1.x); f[5]=(short)f2bf(w1.y); f[6]=(short)f2bf(w1.z); f[7]=(short)f2bf(w1.w);
        }
        wfrag[mt] = f;
    }

    // per-lane spill column mapping (vc -> padded-4 col)
    int c4[3];
    #pragma unroll
    for (int ct = 0; ct < 3; ++ct) {
        int vcw = wv*48 + ct*16 + l15;          // [0,192)
        c4[ct] = (vcw/3)*4 + vcw%3;
    }
    int tri = (((lane % 3)*16) + lane/3) * 4;   // bpermute byte index for output transpose

    // ---- GEMM1: vh = Arow . Bmat^T, fragments streamed from dense K-tiled layouts ----
    const unsigned short* abase = Arow + ((size_t)n0 + l15)*32 + jg*8;
    const unsigned short* bbase = Bmat + ((size_t)vcw0 + l15)*32 + jg*8;
    f32x4 acc[2][3] = {};
    #pragma unroll
    for (int ks = 0; ks < 7; ++ks) {
        bh8 a0 = *(const bh8*)(abase + (size_t)ks*NBATCH*32);
        bh8 a1 = *(const bh8*)(abase + (size_t)ks*NBATCH*32 + 16*32);
        bh8 b0 = *(const bh8*)(bbase + (size_t)ks*VCP*32);
        bh8 b1 = *(const bh8*)(bbase + (size_t)ks*VCP*32 + 16*32);
        bh8 b2 = *(const bh8*)(bbase + (size_t)ks*VCP*32 + 32*32);
        acc[0][0] = __builtin_amdgcn_mfma_f32_16x16x32_bf16(a0, b0, acc[0][0], 0, 0, 0);
        acc[0][1] = __builtin_amdgcn_mfma_f32_16x16x32_bf16(a0, b1, acc[0][1], 0, 0, 0);
        acc[0][2] = __builtin_amdgcn_mfma_f32_16x16x32_bf16(a0, b2, acc[0][2], 0, 0, 0);
        acc[1][0] = __builtin_amdgcn_mfma_f32_16x16x32_bf16(a1, b0, acc[1][0], 0, 0, 0);
        acc[1][1] = __builtin_amdgcn_mfma_f32_16x16x32_bf16(a1, b1, acc[1][1], 0, 0, 0);
        acc[1][2] = __builtin_amdgcn_mfma_f32_16x16x32_bf16(a1, b2, acc[1][2], 0, 0, 0);
    }

    // spill (bf16, padded-4): row = n_local, col = v*4+b
    #pragma unroll
    for (int mt = 0; mt < 2; ++mt)
        #pragma unroll
        for (int ct = 0; ct < 3; ++ct)
            #pragma unroll
            for (int r = 0; r < 4; ++r)
                vhsm[(mt*16 + jg*4 + r)*VST4 + c4[ct]] = f2bf(acc[mt][ct][r]);
    __syncthreads();

    // ---- GEMM2 + apply + transpose + store ----
    const unsigned short* gbase = Gt + ((size_t)(n0 + wv*8))*512 + l15*32 + jg*8;
    #pragma unroll
    for (int nl = 0; nl < 8; ++nl) {
        bh8 gfr = *(const bh8*)(gbase + nl*512);
        int n_loc = wv*8 + nl;
        #pragma unroll
        for (int mt = 0; mt < 4; ++mt) {
            f32x4 z = {0.f, 0.f, 0.f, 0.f};
            f32x4 t = __builtin_amdgcn_mfma_f32_16x16x32_bf16(gfr, wfrag[mt], z, 0, 0, 0);
            u16x4 vh4 = *(const u16x4*)&vhsm[n_loc*VST4 + (mt*16 + l15)*4];
            float p = t[0]*bf2f(vh4[0]) + t[1]*bf2f(vh4[1]) + t[2]*bf2f(vh4[2]) + t[3];
            float pp = __int_as_float(__builtin_amdgcn_ds_bpermute(tri, __float_as_int(p)));
            int col = vc0 + mt*48 + lane;
            if (lane < 48 && col < VC)
                verts[(size_t)(n0 + n_loc)*VC + col] = pp;
        }
    }
}

// ---------------- K_joints: LDS-staged MFMA GEMM  jpart[ks][n][kc] += verts x JbigT ----------------
__global__ __launch_bounds__(256) void k_joints(const float* __restrict__ verts,
                                                const unsigned short* __restrict__ JbigT,
                                                float* __restrict__ jpart) {
    __shared__ __attribute__((aligned(16))) unsigned short vt[32*128];   // 8 KB

    int tid = threadIdx.x;
    int lane = tid & 63, wv = tid >> 6;
    int l15 = lane & 15, jg = lane >> 4;
    int nt = blockIdx.x, ks = blockIdx.y;
    int n0 = nt * 32;
    int step0 = ks * (JCH*4);          // 36 k-steps per slice

    int row[4], c4[4];
    #pragma unroll
    for (int i = 0; i < 4; ++i) {
        int idx = i*256 + tid;         // 1024 16B-units = 32 rows x 32
        row[i] = idx >> 5; c4[i] = idx & 31;
    }

    float2 rg[8];
    auto issue = [&](int ch) {         // coalesced: consecutive lanes -> consecutive 8B
        int k0f = (step0 + ch*4) * 32;
        #pragma unroll
        for (int i = 0; i < 4; ++i) {
            const float* p = verts + (size_t)(n0 + row[i])*VC + k0f + c4[i]*4;
            rg[2*i+0] = *(const float2*)(p);
            rg[2*i+1] = *(const float2*)(p+2);
        }
    };

    issue(0);
    f32x4 acc[2] = {};
    #pragma unroll 1
    for (int ch = 0; ch < JCH; ++ch) {
        __syncthreads();               // prev chunk's fragment reads done
        #pragma unroll
        for (int i = 0; i < 4; ++i) {
            u16x4 w;
            w[0] = f2bf(rg[2*i].x); w[1] = f2bf(rg[2*i].y);
            w[2] = f2bf(rg[2*i+1].x); w[3] = f2bf(rg[2*i+1].y);
            int sidx = (row[i]*128 + c4[i]*4) ^ ((row[i] & 7) << 3);
            *(u16x4*)&vt[sidx] = w;
        }
        __syncthreads();
        if (ch + 1 < JCH) issue(ch + 1);   // overlap next-stage loads with MFMAs
        #pragma unroll
        for (int kk = 0; kk < 4; ++kk) {
            int r0 = l15, r1 = 16 + l15;
            bh8 a0 = *(const bh8*)&vt[(r0*128 + kk*32 + jg*8) ^ ((r0 & 7) << 3)];
            bh8 a1 = *(const bh8*)&vt[(r1*128 + kk*32 + jg*8) ^ ((r1 & 7) << 3)];
            bh8 b  = *(const bh8*)(JbigT + ((size_t)(step0 + ch*4 + kk)*64 + wv*16 + l15)*32 + jg*8);
            acc[0] = __builtin_amdgcn_mfma_f32_16x16x32_bf16(a0, b, acc[0], 0, 0, 0);
            acc[1] = __builtin_amdgcn_mfma_f32_16x16x32_bf16(a1, b, acc[1], 0, 0, 0);
        }
    }
    // D: col=lane&15 (kc within wave), row=(lane>>4)*4+r (n within 16-tile)
    float* jp = jpart + ((size_t)ks*NBATCH + n0)*64 + wv*16 + l15;
    #pragma unroll
    for (int mt = 0; mt < 2; ++mt)
        #pragma unroll
        for (int r = 0; r < 4; ++r)
            jp[(size_t)(mt*16 + jg*4 + r)*64] = acc[mt][r];
}

// ---------------- K_jred: joints[n, i] = sum_ks jpart[ks][n][i] ----------------
__global__ __launch_bounds__(256) void k_jred(const float* __restrict__ jpart,
                                              float* __restrict__ joints) {
    int idx = blockIdx.x*256 + threadIdx.x;
    if (idx >= NBATCH*NK*3) return;
    int n = idx / (NK*3), i = idx - n*(NK*3);
    float s = 0.f;
    #pragma unroll
    for (int ks = 0; ks < JSP; ++ks)
        s += jpart[((size_t)ks*NBATCH + n)*64 + i];
    joints[idx] = s;
}

extern "C" void kernel_launch(void* const* d_in, const int* in_sizes, int n_in,
                              void* d_out, int out_size, void* d_ws, size_t ws_size,
                              hipStream_t stream) {
    const float* beta  = (const float*)d_in[0];
    const float* theta = (const float*)d_in[1];
    const float* trans = (const float*)d_in[2];
    const float* sdirs = (const float*)d_in[3];
    const float* vtmpl = (const float*)d_in[4];
    const float* jregJ = (const float*)d_in[5];
    const float* pdirs = (const float*)d_in[6];
    const float* wgts  = (const float*)d_in[7];
    const float* jregK = (const float*)d_in[8];

    float* verts  = (float*)d_out;
    float* joints = verts + (size_t)NBATCH * VC;

    char* ws = (char*)d_ws;
    float*          JB    = (float*)ws;                                      // 4096 B (zeroed)
    unsigned short* Arow  = (unsigned short*)(ws + 4096);                    // 917504 B
    unsigned short* Gt    = (unsigned short*)(ws + 4096 + 917504);           // 2097152 B
    unsigned short* Bmat  = (unsigned short*)(ws + 4096 + 917504 + 2097152); // 9289728 B
    unsigned short* JbigT = (unsigned short*)(ws + 4096 + 917504 + 2097152 + 9289728); // 648*64*32*2 = 2654208
    float*          jpart = (float*)(ws + 4096 + 917504 + 2097152 + 9289728 + 2654208); // 18*2048*64*4 = 9437184

    hipMemsetAsync(JB, 0, 4096, stream);

    k_prep <<<792 + 18144 + 5184, 256, 0, stream>>>(jregJ, vtmpl, sdirs, pdirs, jregK, JB, Bmat, JbigT);
    k_pern <<<NBATCH, 64, 0, stream>>>(beta, theta, trans, JB, Arow, Gt);
    dim3 g4(NBATCH/BN, (V + BV - 1)/BV);   // (64, 108), x-fastest keeps B slice L2-hot
    k_main <<<g4, 256, 0, stream>>>(Arow, Bmat, Gt, wgts, verts);
    dim3 g5(NBATCH/BN, JSP);            // (64, 18)
    k_joints<<<g5, 256, 0, stream>>>(verts, JbigT, jpart);
    k_jred <<<(NBATCH*NK*3 + 255)/256, 256, 0, stream>>>(jpart, joints);
}